// Round 1
// baseline (629.193 us; speedup 1.0000x reference)
//
#include <hip/hip_runtime.h>
#include <stdint.h>

#define B 64
#define G 32
#define A 25600
#define NC 2
#define NL 5
#define IOU_T 0.5f
#define VAR_C 0.1f
#define VAR_S 0.2f

__device__ __forceinline__ float sl1(float x) {
    float ax = fabsf(x);
    return ax < 1.0f ? 0.5f * ax * ax : ax - 0.5f;
}

// ---------------------------------------------------------------------------
// Kernel 1: build matches[b][a] (int8). Values: -1 none, 0..31 threshold match,
// 64+g forced match (best anchor per gt).  One block per batch image.
// ---------------------------------------------------------------------------
__global__ __launch_bounds__(256) void match_kernel(
    const float* __restrict__ anchors, const float* __restrict__ gt_boxes,
    const int* __restrict__ gt_labels, signed char* __restrict__ matches)
{
    const int b = blockIdx.x;
    const int tid = threadIdx.x;
    __shared__ float gx0[G], gy0[G], gx1[G], gy1[G], garea[G];
    __shared__ int gvalid[G];
    __shared__ unsigned long long sbest[G];

    if (tid < G) {
        const float* gb = gt_boxes + (b * G + tid) * 4;
        float x0 = gb[0], y0 = gb[1], x1 = gb[2], y1 = gb[3];
        gx0[tid] = x0; gy0[tid] = y0; gx1[tid] = x1; gy1[tid] = y1;
        garea[tid] = (x1 - x0) * (y1 - y0);
        gvalid[tid] = gt_labels[b * G + tid] > 0;
        sbest[tid] = 0ULL;
    }
    __syncthreads();

    signed char* mrow = matches + (size_t)b * A;

    for (int a = tid; a < A; a += 256) {
        float cx = anchors[a * 4 + 0], cy = anchors[a * 4 + 1];
        float w  = anchors[a * 4 + 2], h  = anchors[a * 4 + 3];
        float ax0 = cx - w * 0.5f, ay0 = cy - h * 0.5f;
        float ax1 = cx + w * 0.5f, ay1 = cy + h * 0.5f;
        float aa = (ax1 - ax0) * (ay1 - ay0);   // mirror reference float path

        float best_iou = -2.0f; int best_g = 0;
        #pragma unroll
        for (int g = 0; g < G; ++g) {
            float iou;
            if (gvalid[g]) {
                float tlx = fmaxf(gx0[g], ax0), tly = fmaxf(gy0[g], ay0);
                float brx = fminf(gx1[g], ax1), bry = fminf(gy1[g], ay1);
                float iw = fmaxf(brx - tlx, 0.0f), ih = fmaxf(bry - tly, 0.0f);
                float inter = iw * ih;
                iou = inter / (garea[g] + aa - inter + 1e-9f);
                // per-gt best anchor: max iou, tie -> lowest anchor idx
                unsigned long long key =
                    ((unsigned long long)__float_as_uint(iou) << 32) |
                    (unsigned)(0xFFFFFFFFu - (unsigned)a);
                if (key > sbest[g]) atomicMax(&sbest[g], key);
            } else {
                iou = -1.0f;   // invalid rows participate in per-anchor argmax as -1
            }
            if (iou > best_iou) { best_iou = iou; best_g = g; }  // first-max wins
        }
        mrow[a] = (best_iou >= IOU_T) ? (signed char)best_g : (signed char)(-1);
    }
    __syncthreads();

    if (tid == 0) {
        // forced matches: sequential g ascending (last gt wins on duplicates),
        // threshold matches (0..31) take precedence.
        for (int g = 0; g < G; ++g) {
            if (!gvalid[g]) continue;
            unsigned a = 0xFFFFFFFFu - (unsigned)(sbest[g] & 0xFFFFFFFFu);
            signed char v = mrow[a];
            if (v < 0 || v >= 64) mrow[a] = (signed char)(64 + g);
        }
    }
}

// ---------------------------------------------------------------------------
// Kernel 2: per-batch loss partials. One block per batch image.
// partials[b*8 + {0:pos_sum,1:box_sum,2:lmk_sum,3:gaze_sum,4:neg_sum,
//                 5:num_pos_f,6:nface_f}]
// ---------------------------------------------------------------------------
__global__ __launch_bounds__(256) void loss_kernel(
    const float* __restrict__ cls_logits, const float* __restrict__ box_preds,
    const float* __restrict__ lmk_preds, const float* __restrict__ gaze_preds,
    const float* __restrict__ anchors, const float* __restrict__ gt_boxes,
    const int* __restrict__ gt_labels, const float* __restrict__ gt_lmk,
    const float* __restrict__ gt_gaze, const signed char* __restrict__ matches,
    float* __restrict__ partials)
{
    const int b = blockIdx.x, tid = threadIdx.x;
    __shared__ float sgb[G * 4], slmk[G * NL * 2], sgz[G * 2];
    __shared__ int slab[G];
    __shared__ float red[256];
    __shared__ unsigned hist[256];
    __shared__ unsigned s_pfx, s_k;

    for (int i = tid; i < G * 4; i += 256) sgb[i] = gt_boxes[b * G * 4 + i];
    for (int i = tid; i < G * NL * 2; i += 256) slmk[i] = gt_lmk[b * G * NL * 2 + i];
    for (int i = tid; i < G * 2; i += 256) sgz[i] = gt_gaze[b * G * 2 + i];
    if (tid < G) slab[tid] = gt_labels[b * G + tid];
    __syncthreads();

    const signed char* mrow = matches + (size_t)b * A;
    const float* lrow = cls_logits + (size_t)b * A * NC;

    auto redf = [&](float v) -> float {
        red[tid] = v; __syncthreads();
        for (int s = 128; s > 0; s >>= 1) {
            if (tid < s) red[tid] += red[tid + s];
            __syncthreads();
        }
        float r = red[0]; __syncthreads();
        return r;
    };
    auto redu = [&](unsigned v) -> unsigned {
        hist[tid] = v; __syncthreads();
        for (int s = 128; s > 0; s >>= 1) {
            if (tid < s) hist[tid] += hist[tid + s];
            __syncthreads();
        }
        unsigned r = hist[0]; __syncthreads();
        return r;
    };

    // ---- pass 1: positive-side sums + counts ----
    float pos_sum = 0, box_sum = 0, lmk_sum = 0, gaze_sum = 0;
    unsigned pos_cnt = 0, face_cnt = 0;
    for (int a = tid; a < A; a += 256) {
        int v = mrow[a];
        if (v < 0) continue;
        int m = v & 31;
        float x0 = lrow[a * 2], x1 = lrow[a * 2 + 1];
        float mx = fmaxf(x0, x1);
        float lse = mx + logf(expf(x0 - mx) + expf(x1 - mx));
        int lab = slab[m];                 // >0 for any matched gt
        float xc = (lab >= 1) ? x1 : x0;   // NC==2
        pos_sum += lse - xc;
        pos_cnt++;
        float dcx = anchors[a * 4], dcy = anchors[a * 4 + 1];
        float dw  = anchors[a * 4 + 2], dh = anchors[a * 4 + 3];
        float bx0 = sgb[m * 4], by0 = sgb[m * 4 + 1];
        float bx1 = sgb[m * 4 + 2], by1 = sgb[m * 4 + 3];
        float gcx = (bx0 + bx1) * 0.5f, gcy = (by0 + by1) * 0.5f;
        float gw = bx1 - bx0, gh = by1 - by0;
        float off0 = ((gcx - dcx) / dw) / VAR_C;
        float off1 = ((gcy - dcy) / dh) / VAR_C;
        float off2 = logf(fmaxf(gw / dw, 1e-6f)) / VAR_S;
        float off3 = logf(fmaxf(gh / dh, 1e-6f)) / VAR_S;
        const float* bp = box_preds + ((size_t)b * A + a) * 4;
        box_sum += sl1(bp[0] - off0) + sl1(bp[1] - off1) +
                   sl1(bp[2] - off2) + sl1(bp[3] - off3);
        if (lab == 1) {  // FACE
            face_cnt++;
            const float* lp = lmk_preds + ((size_t)b * A + a) * (NL * 2);
            #pragma unroll
            for (int i = 0; i < NL; ++i) {
                float tx = ((slmk[m * NL * 2 + 2 * i] - dcx) / dw) / VAR_C;
                float ty = ((slmk[m * NL * 2 + 2 * i + 1] - dcy) / dh) / VAR_C;
                lmk_sum += sl1(lp[2 * i] - tx) + sl1(lp[2 * i + 1] - ty);
            }
            const float* gp = gaze_preds + ((size_t)b * A + a) * 2;
            gaze_sum += sl1(gp[0] - sgz[m * 2]) + sl1(gp[1] - sgz[m * 2 + 1]);
        }
    }
    pos_sum  = redf(pos_sum);
    box_sum  = redf(box_sum);
    lmk_sum  = redf(lmk_sum);
    gaze_sum = redf(gaze_sum);
    unsigned pos_t  = redu(pos_cnt);
    unsigned face_t = redu(face_cnt);

    unsigned num_pos = pos_t > 1u ? pos_t : 1u;
    unsigned neg_cnt = (unsigned)A - pos_t;
    unsigned k = 3u * num_pos; if (neg_cnt < k) k = neg_cnt;

    // ---- radix select: k-th largest negative cls loss ----
    unsigned pfx = 0, kk = k;
    for (int p = 0; p < 4; ++p) {
        hist[tid] = 0; __syncthreads();
        const int shift = 24 - 8 * p;
        for (int a = tid; a < A; a += 256) {
            if (mrow[a] >= 0) continue;
            float x0 = lrow[a * 2], x1 = lrow[a * 2 + 1];
            float mx = fmaxf(x0, x1);
            float closs = mx + logf(expf(x0 - mx) + expf(x1 - mx)) - x0;
            unsigned bits = __float_as_uint(closs);
            unsigned key = bits ^ ((bits & 0x80000000u) ? 0xFFFFFFFFu : 0x80000000u);
            if (p == 0 || (key >> (shift + 8)) == pfx)
                atomicAdd(&hist[(key >> shift) & 0xFFu], 1u);
        }
        __syncthreads();
        if (tid == 0) {
            unsigned cum = 0, sel = 0, kn = kk;
            for (int bin = 255; bin >= 0; --bin) {
                unsigned c = hist[bin];
                if (cum + c >= kk) { sel = (unsigned)bin; kn = kk - cum; break; }
                cum += c;
            }
            s_pfx = (pfx << 8) | sel; s_k = kn;
        }
        __syncthreads();
        pfx = s_pfx; kk = s_k;
    }
    const unsigned Tkey = pfx;
    const unsigned krem = kk;
    unsigned bitsT = (Tkey & 0x80000000u) ? (Tkey ^ 0x80000000u) : ~Tkey;
    const float Tval = __uint_as_float(bitsT);

    float nsum = 0;
    for (int a = tid; a < A; a += 256) {
        if (mrow[a] >= 0) continue;
        float x0 = lrow[a * 2], x1 = lrow[a * 2 + 1];
        float mx = fmaxf(x0, x1);
        float closs = mx + logf(expf(x0 - mx) + expf(x1 - mx)) - x0;
        unsigned bits = __float_as_uint(closs);
        unsigned key = bits ^ ((bits & 0x80000000u) ? 0xFFFFFFFFu : 0x80000000u);
        if (key > Tkey) nsum += closs;
    }
    float neg_sum = redf(nsum) + (float)krem * Tval;

    if (tid == 0) {
        float* pr = partials + b * 8;
        pr[0] = pos_sum; pr[1] = box_sum; pr[2] = lmk_sum; pr[3] = gaze_sum;
        pr[4] = neg_sum;
        pr[5] = (float)num_pos;
        pr[6] = (float)(face_t > 1u ? face_t : 1u);
    }
}

// ---------------------------------------------------------------------------
// Kernel 3: combine per-batch partials -> 5 scalar outputs.
// ---------------------------------------------------------------------------
__global__ void finalize_kernel(const float* __restrict__ partials,
                                float* __restrict__ out)
{
    int t = threadIdx.x;  // 64 threads = 1 wave
    float ps = partials[t * 8 + 0], bs = partials[t * 8 + 1];
    float ls = partials[t * 8 + 2], gs = partials[t * 8 + 3];
    float ns = partials[t * 8 + 4], npos = partials[t * 8 + 5];
    float nf = partials[t * 8 + 6];
    for (int o = 32; o > 0; o >>= 1) {
        ps += __shfl_down(ps, o); bs += __shfl_down(bs, o);
        ls += __shfl_down(ls, o); gs += __shfl_down(gs, o);
        ns += __shfl_down(ns, o); npos += __shfl_down(npos, o);
        nf += __shfl_down(nf, o);
    }
    if (t == 0) {
        float tc = (ps + ns) / npos;
        float tb = bs / npos;
        float tl = ls / nf;
        float tg = gs / nf;
        out[0] = tc + 1.0f * tb + 0.5f * tl + 1.0f * tg;
        out[1] = tc; out[2] = tb; out[3] = tl; out[4] = tg;
    }
}

extern "C" void kernel_launch(void* const* d_in, const int* in_sizes, int n_in,
                              void* d_out, int out_size, void* d_ws, size_t ws_size,
                              hipStream_t stream) {
    const float* cls_logits = (const float*)d_in[0];
    const float* box_preds  = (const float*)d_in[1];
    const float* lmk_preds  = (const float*)d_in[2];
    const float* gaze_preds = (const float*)d_in[3];
    const float* anchors    = (const float*)d_in[4];
    const float* gt_boxes   = (const float*)d_in[5];
    const int*   gt_labels  = (const int*)d_in[6];
    const float* gt_lmk     = (const float*)d_in[7];
    const float* gt_gaze    = (const float*)d_in[8];

    signed char* matches = (signed char*)d_ws;
    float* partials = (float*)((char*)d_ws + (size_t)B * A);  // 1,638,400 B offset
    float* out = (float*)d_out;

    hipLaunchKernelGGL(match_kernel, dim3(B), dim3(256), 0, stream,
                       anchors, gt_boxes, gt_labels, matches);
    hipLaunchKernelGGL(loss_kernel, dim3(B), dim3(256), 0, stream,
                       cls_logits, box_preds, lmk_preds, gaze_preds, anchors,
                       gt_boxes, gt_labels, gt_lmk, gt_gaze, matches, partials);
    hipLaunchKernelGGL(finalize_kernel, dim3(1), dim3(64), 0, stream,
                       partials, out);
}

// Round 2
// 465.301 us; speedup vs baseline: 1.3522x; 1.3522x over previous
//
#include <hip/hip_runtime.h>
#include <stdint.h>

#define B 64
#define G 32
#define A 25600
#define NC 2
#define NL 5
#define IOU_T 0.5f
#define VAR_C 0.1f
#define VAR_S 0.2f

#define MSPLIT 32
#define MCH (A / MSPLIT)    // 800 anchors per match block
#define LSPLIT 16
#define LCH (A / LSPLIT)    // 1600 anchors per loss block
#define PF 8                // fields per psplit record

__device__ __forceinline__ float sl1(float x) {
    float ax = fabsf(x);
    return ax < 1.0f ? 0.5f * ax * ax : ax - 0.5f;
}

// ---------------------------------------------------------------------------
// K0: zero the per-gt best-anchor table.
// ---------------------------------------------------------------------------
__global__ void init_kernel(unsigned long long* __restrict__ gbest) {
    int i = blockIdx.x * blockDim.x + threadIdx.x;
    if (i < B * G) gbest[i] = 0ULL;
}

// ---------------------------------------------------------------------------
// K1: matches[b][a] threshold part + per-gt best via atomicMax.
// grid (B, MSPLIT) x 256.
// ---------------------------------------------------------------------------
__global__ __launch_bounds__(256) void match_kernel(
    const float* __restrict__ anchors, const float* __restrict__ gt_boxes,
    const int* __restrict__ gt_labels, signed char* __restrict__ matches,
    unsigned long long* __restrict__ gbest)
{
    const int b = blockIdx.x, s = blockIdx.y, tid = threadIdx.x;
    __shared__ float gx0[G], gy0[G], gx1[G], gy1[G], garea[G];
    __shared__ int gvalid[G];
    __shared__ unsigned long long sbest[G];

    if (tid < G) {
        const float* gb = gt_boxes + (b * G + tid) * 4;
        float x0 = gb[0], y0 = gb[1], x1 = gb[2], y1 = gb[3];
        gx0[tid] = x0; gy0[tid] = y0; gx1[tid] = x1; gy1[tid] = y1;
        garea[tid] = (x1 - x0) * (y1 - y0);
        gvalid[tid] = gt_labels[b * G + tid] > 0;
        sbest[tid] = 0ULL;
    }
    __syncthreads();

    signed char* mrow = matches + (size_t)b * A;
    const int a0 = s * MCH, a1 = a0 + MCH;

    for (int a = a0 + tid; a < a1; a += 256) {
        float4 an = *(const float4*)(anchors + a * 4);
        float ax0 = an.x - an.z * 0.5f, ay0 = an.y - an.w * 0.5f;
        float ax1 = an.x + an.z * 0.5f, ay1 = an.y + an.w * 0.5f;
        float aa = (ax1 - ax0) * (ay1 - ay0);   // mirror reference float path

        float best_iou = -2.0f; int best_g = 0;
        #pragma unroll
        for (int g = 0; g < G; ++g) {
            float iou;
            if (gvalid[g]) {
                float tlx = fmaxf(gx0[g], ax0), tly = fmaxf(gy0[g], ay0);
                float brx = fminf(gx1[g], ax1), bry = fminf(gy1[g], ay1);
                float iw = fmaxf(brx - tlx, 0.0f), ih = fmaxf(bry - tly, 0.0f);
                float inter = iw * ih;
                iou = inter / (garea[g] + aa - inter + 1e-9f);
                unsigned long long key =
                    ((unsigned long long)__float_as_uint(iou) << 32) |
                    (unsigned)(0xFFFFFFFFu - (unsigned)a);
                if (key > sbest[g]) atomicMax(&sbest[g], key);
            } else {
                iou = -1.0f;
            }
            if (iou > best_iou) { best_iou = iou; best_g = g; }  // first-max wins
        }
        mrow[a] = (best_iou >= IOU_T) ? (signed char)best_g : (signed char)(-1);
    }
    __syncthreads();
    if (tid < G && gvalid[tid] && sbest[tid] != 0ULL)
        atomicMax(&gbest[b * G + tid], sbest[tid]);
}

// ---------------------------------------------------------------------------
// K2: apply forced matches (sequential per batch, g ascending = last-wins).
// ---------------------------------------------------------------------------
__global__ void force_kernel(const unsigned long long* __restrict__ gbest,
                             const int* __restrict__ gt_labels,
                             signed char* __restrict__ matches)
{
    int b = threadIdx.x;
    if (b >= B) return;
    signed char* mrow = matches + (size_t)b * A;
    for (int g = 0; g < G; ++g) {
        if (gt_labels[b * G + g] <= 0) continue;
        unsigned a = 0xFFFFFFFFu - (unsigned)(gbest[b * G + g] & 0xFFFFFFFFu);
        signed char v = mrow[a];
        if (v < 0 || v >= 64) mrow[a] = (signed char)(64 + g);
    }
}

// ---------------------------------------------------------------------------
// K3: positive-side partial sums per (b, split) + negative-loss keys.
// grid (B, LSPLIT) x 256.  psplit fields: 0 pos_sum 1 box 2 lmk 3 gaze
//                                         4 pos_cnt 5 face_cnt
// ---------------------------------------------------------------------------
__global__ __launch_bounds__(256) void loss_split_kernel(
    const float* __restrict__ cls_logits, const float* __restrict__ box_preds,
    const float* __restrict__ lmk_preds, const float* __restrict__ gaze_preds,
    const float* __restrict__ anchors, const float* __restrict__ gt_boxes,
    const int* __restrict__ gt_labels, const float* __restrict__ gt_lmk,
    const float* __restrict__ gt_gaze, const signed char* __restrict__ matches,
    unsigned* __restrict__ negkey, float* __restrict__ psplit)
{
    const int b = blockIdx.x, s = blockIdx.y, tid = threadIdx.x;
    __shared__ float sgb[G * 4], slmk[G * NL * 2], sgz[G * 2];
    __shared__ int slab[G];
    __shared__ float red[256];

    for (int i = tid; i < G * 4; i += 256) sgb[i] = gt_boxes[b * G * 4 + i];
    for (int i = tid; i < G * NL * 2; i += 256) slmk[i] = gt_lmk[b * G * NL * 2 + i];
    for (int i = tid; i < G * 2; i += 256) sgz[i] = gt_gaze[b * G * 2 + i];
    if (tid < G) slab[tid] = gt_labels[b * G + tid];
    __syncthreads();

    const signed char* mrow = matches + (size_t)b * A;
    const float* lrow = cls_logits + (size_t)b * A * NC;
    unsigned* krow = negkey + (size_t)b * A;

    float pos_sum = 0, box_sum = 0, lmk_sum = 0, gaze_sum = 0;
    float pos_cnt = 0, face_cnt = 0;
    const int a0 = s * LCH, a1 = a0 + LCH;

    for (int a = a0 + tid; a < a1; a += 256) {
        int v = mrow[a];
        float x0 = lrow[a * 2], x1 = lrow[a * 2 + 1];
        float mx = fmaxf(x0, x1);
        float lse = mx + logf(expf(x0 - mx) + expf(x1 - mx));
        unsigned key = 0;
        if (v < 0) {
            float closs = lse - x0;   // label 0
            unsigned bits = __float_as_uint(closs);
            key = bits ^ ((bits & 0x80000000u) ? 0xFFFFFFFFu : 0x80000000u);
        } else {
            int m = v & 31;
            int lab = slab[m];
            float xc = (lab >= 1) ? x1 : x0;   // NC==2
            pos_sum += lse - xc;
            pos_cnt += 1.0f;
            float4 an = *(const float4*)(anchors + a * 4);
            float dcx = an.x, dcy = an.y, dw = an.z, dh = an.w;
            float bx0 = sgb[m * 4], by0 = sgb[m * 4 + 1];
            float bx1 = sgb[m * 4 + 2], by1 = sgb[m * 4 + 3];
            float gcx = (bx0 + bx1) * 0.5f, gcy = (by0 + by1) * 0.5f;
            float gw = bx1 - bx0, gh = by1 - by0;
            float off0 = ((gcx - dcx) / dw) / VAR_C;
            float off1 = ((gcy - dcy) / dh) / VAR_C;
            float off2 = logf(fmaxf(gw / dw, 1e-6f)) / VAR_S;
            float off3 = logf(fmaxf(gh / dh, 1e-6f)) / VAR_S;
            float4 bp = *(const float4*)(box_preds + ((size_t)b * A + a) * 4);
            box_sum += sl1(bp.x - off0) + sl1(bp.y - off1) +
                       sl1(bp.z - off2) + sl1(bp.w - off3);
            if (lab == 1) {  // FACE
                face_cnt += 1.0f;
                const float* lp = lmk_preds + ((size_t)b * A + a) * (NL * 2);
                #pragma unroll
                for (int i = 0; i < NL; ++i) {
                    float tx = ((slmk[m * NL * 2 + 2 * i] - dcx) / dw) / VAR_C;
                    float ty = ((slmk[m * NL * 2 + 2 * i + 1] - dcy) / dh) / VAR_C;
                    lmk_sum += sl1(lp[2 * i] - tx) + sl1(lp[2 * i + 1] - ty);
                }
                const float* gp = gaze_preds + ((size_t)b * A + a) * 2;
                gaze_sum += sl1(gp[0] - sgz[m * 2]) + sl1(gp[1] - sgz[m * 2 + 1]);
            }
        }
        krow[a] = key;
    }

    auto redf = [&](float v) -> float {
        red[tid] = v; __syncthreads();
        for (int st = 128; st > 0; st >>= 1) {
            if (tid < st) red[tid] += red[tid + st];
            __syncthreads();
        }
        float r = red[0]; __syncthreads();
        return r;
    };
    float f0 = redf(pos_sum), f1 = redf(box_sum), f2 = redf(lmk_sum);
    float f3 = redf(gaze_sum), f4 = redf(pos_cnt), f5 = redf(face_cnt);
    if (tid == 0) {
        float* pr = psplit + (b * LSPLIT + s) * PF;
        pr[0] = f0; pr[1] = f1; pr[2] = f2; pr[3] = f3; pr[4] = f4; pr[5] = f5;
    }
}

// ---------------------------------------------------------------------------
// K4: per-batch: reduce split partials, radix-select k-th largest negative
// loss from precomputed keys, sum top-k. grid B x 256.
// ---------------------------------------------------------------------------
__global__ __launch_bounds__(256) void select_kernel(
    const unsigned* __restrict__ negkey, const float* __restrict__ psplit,
    float* __restrict__ partials)
{
    const int b = blockIdx.x, tid = threadIdx.x;
    __shared__ float acc[PF];
    __shared__ unsigned hist[256];
    __shared__ unsigned s_pfx, s_k;
    __shared__ float red[256];

    if (tid < 6) {
        float v = 0;
        for (int s = 0; s < LSPLIT; ++s) v += psplit[(b * LSPLIT + s) * PF + tid];
        acc[tid] = v;
    }
    __syncthreads();

    unsigned pos_t = (unsigned)acc[4];
    unsigned face_t = (unsigned)acc[5];
    unsigned num_pos = pos_t > 1u ? pos_t : 1u;
    unsigned neg_cnt = (unsigned)A - pos_t;
    unsigned k = 3u * num_pos; if (neg_cnt < k) k = neg_cnt;

    const unsigned* krow = negkey + (size_t)b * A;
    unsigned pfx = 0, kk = k;
    for (int p = 0; p < 4; ++p) {
        hist[tid] = 0; __syncthreads();
        const int shift = 24 - 8 * p;
        for (int a = tid; a < A; a += 256) {
            unsigned key = krow[a];
            if (key != 0 && (p == 0 || (key >> (shift + 8)) == pfx))
                atomicAdd(&hist[(key >> shift) & 0xFFu], 1u);
        }
        __syncthreads();
        if (tid == 0) {
            unsigned cum = 0, sel = 0, kn = kk;
            for (int bin = 255; bin >= 0; --bin) {
                unsigned c = hist[bin];
                if (cum + c >= kk) { sel = (unsigned)bin; kn = kk - cum; break; }
                cum += c;
            }
            s_pfx = (pfx << 8) | sel; s_k = kn;
        }
        __syncthreads();
        pfx = s_pfx; kk = s_k;
    }
    const unsigned Tkey = pfx;
    const unsigned krem = kk;
    unsigned bitsT = (Tkey & 0x80000000u) ? (Tkey ^ 0x80000000u) : ~Tkey;
    const float Tval = __uint_as_float(bitsT);

    float nsum = 0;
    for (int a = tid; a < A; a += 256) {
        unsigned key = krow[a];
        if (key > Tkey) {
            unsigned bits = (key & 0x80000000u) ? (key ^ 0x80000000u) : ~key;
            nsum += __uint_as_float(bits);
        }
    }
    red[tid] = nsum; __syncthreads();
    for (int st = 128; st > 0; st >>= 1) {
        if (tid < st) red[tid] += red[tid + st];
        __syncthreads();
    }

    if (tid == 0) {
        float* pr = partials + b * PF;
        pr[0] = acc[0]; pr[1] = acc[1]; pr[2] = acc[2]; pr[3] = acc[3];
        pr[4] = red[0] + (float)krem * Tval;
        pr[5] = (float)num_pos;
        pr[6] = (float)(face_t > 1u ? face_t : 1u);
    }
}

// ---------------------------------------------------------------------------
// K5: combine per-batch partials -> 5 scalar outputs.
// ---------------------------------------------------------------------------
__global__ void finalize_kernel(const float* __restrict__ partials,
                                float* __restrict__ out)
{
    int t = threadIdx.x;  // 64 threads = 1 wave
    float ps = partials[t * PF + 0], bs = partials[t * PF + 1];
    float ls = partials[t * PF + 2], gs = partials[t * PF + 3];
    float ns = partials[t * PF + 4], npos = partials[t * PF + 5];
    float nf = partials[t * PF + 6];
    for (int o = 32; o > 0; o >>= 1) {
        ps += __shfl_down(ps, o); bs += __shfl_down(bs, o);
        ls += __shfl_down(ls, o); gs += __shfl_down(gs, o);
        ns += __shfl_down(ns, o); npos += __shfl_down(npos, o);
        nf += __shfl_down(nf, o);
    }
    if (t == 0) {
        float tc = (ps + ns) / npos;
        float tb = bs / npos;
        float tl = ls / nf;
        float tg = gs / nf;
        out[0] = tc + 1.0f * tb + 0.5f * tl + 1.0f * tg;
        out[1] = tc; out[2] = tb; out[3] = tl; out[4] = tg;
    }
}

extern "C" void kernel_launch(void* const* d_in, const int* in_sizes, int n_in,
                              void* d_out, int out_size, void* d_ws, size_t ws_size,
                              hipStream_t stream) {
    const float* cls_logits = (const float*)d_in[0];
    const float* box_preds  = (const float*)d_in[1];
    const float* lmk_preds  = (const float*)d_in[2];
    const float* gaze_preds = (const float*)d_in[3];
    const float* anchors    = (const float*)d_in[4];
    const float* gt_boxes   = (const float*)d_in[5];
    const int*   gt_labels  = (const int*)d_in[6];
    const float* gt_lmk     = (const float*)d_in[7];
    const float* gt_gaze    = (const float*)d_in[8];

    char* ws = (char*)d_ws;
    signed char* matches = (signed char*)ws;            ws += (size_t)B * A;            // 1.6 MB
    unsigned long long* gbest = (unsigned long long*)ws; ws += (size_t)B * G * 8;        // 16 KB
    unsigned* negkey = (unsigned*)ws;                    ws += (size_t)B * A * 4;        // 6.5 MB
    float* psplit = (float*)ws;                          ws += (size_t)B * LSPLIT * PF * 4;
    float* partials = (float*)ws;
    float* out = (float*)d_out;

    hipLaunchKernelGGL(init_kernel, dim3((B * G + 255) / 256), dim3(256), 0, stream, gbest);
    hipLaunchKernelGGL(match_kernel, dim3(B, MSPLIT), dim3(256), 0, stream,
                       anchors, gt_boxes, gt_labels, matches, gbest);
    hipLaunchKernelGGL(force_kernel, dim3(1), dim3(64), 0, stream,
                       gbest, gt_labels, matches);
    hipLaunchKernelGGL(loss_split_kernel, dim3(B, LSPLIT), dim3(256), 0, stream,
                       cls_logits, box_preds, lmk_preds, gaze_preds, anchors,
                       gt_boxes, gt_labels, gt_lmk, gt_gaze, matches, negkey, psplit);
    hipLaunchKernelGGL(select_kernel, dim3(B), dim3(256), 0, stream,
                       negkey, psplit, partials);
    hipLaunchKernelGGL(finalize_kernel, dim3(1), dim3(64), 0, stream,
                       partials, out);
}

// Round 3
// 241.964 us; speedup vs baseline: 2.6004x; 1.9230x over previous
//
#include <hip/hip_runtime.h>
#include <stdint.h>

#define B 64
#define G 32
#define A 25600
#define NC 2
#define NL 5
#define IOU_T 0.5f
#define VAR_C 0.1f
#define VAR_S 0.2f

#define MSPLIT 32
#define MCH (A / MSPLIT)    // 800 anchors per match block
#define LSPLIT 16
#define LCH (A / LSPLIT)    // 1600 anchors per loss block
#define PF 8                // fields per psplit record

__device__ __forceinline__ float sl1(float x) {
    float ax = fabsf(x);
    return ax < 1.0f ? 0.5f * ax * ax : ax - 0.5f;
}

// ---------------------------------------------------------------------------
// K0: zero the per-gt best-anchor table.
// ---------------------------------------------------------------------------
__global__ void init_kernel(unsigned long long* __restrict__ gbest) {
    int i = blockIdx.x * blockDim.x + threadIdx.x;
    if (i < B * G) gbest[i] = 0ULL;
}

// ---------------------------------------------------------------------------
// K1: grid (B, MSPLIT) x 256.
// Pass 1: per-anchor argmax over gts (registers only) -> matches[b][a].
// Pass 2: per-gt argmax over this block's anchors; each wave owns 8 gts,
//         register maxes + shfl reduce + ONE global atomicMax per (wave,gt).
// No LDS atomics anywhere.
// ---------------------------------------------------------------------------
__global__ __launch_bounds__(256) void match_kernel(
    const float* __restrict__ anchors, const float* __restrict__ gt_boxes,
    const int* __restrict__ gt_labels, signed char* __restrict__ matches,
    unsigned long long* __restrict__ gbest)
{
    const int b = blockIdx.x, s = blockIdx.y, tid = threadIdx.x;
    __shared__ float gx0[G], gy0[G], gx1[G], gy1[G], garea[G];
    __shared__ int gvalid[G];

    if (tid < G) {
        const float* gb = gt_boxes + (b * G + tid) * 4;
        float x0 = gb[0], y0 = gb[1], x1 = gb[2], y1 = gb[3];
        gx0[tid] = x0; gy0[tid] = y0; gx1[tid] = x1; gy1[tid] = y1;
        garea[tid] = (x1 - x0) * (y1 - y0);
        gvalid[tid] = gt_labels[b * G + tid] > 0;
    }
    __syncthreads();

    signed char* mrow = matches + (size_t)b * A;
    const int a0 = s * MCH, a1 = a0 + MCH;

    // ---- pass 1: per-anchor best gt ----
    for (int a = a0 + tid; a < a1; a += 256) {
        float4 an = *(const float4*)(anchors + a * 4);
        float ax0 = an.x - an.z * 0.5f, ay0 = an.y - an.w * 0.5f;
        float ax1 = an.x + an.z * 0.5f, ay1 = an.y + an.w * 0.5f;
        float aa = (ax1 - ax0) * (ay1 - ay0);   // mirror reference float path

        float best_iou = -2.0f; int best_g = 0;
        #pragma unroll
        for (int g = 0; g < G; ++g) {
            float iou = -1.0f;
            if (gvalid[g]) {
                float tlx = fmaxf(gx0[g], ax0), tly = fmaxf(gy0[g], ay0);
                float brx = fminf(gx1[g], ax1), bry = fminf(gy1[g], ay1);
                float iw = fmaxf(brx - tlx, 0.0f), ih = fmaxf(bry - tly, 0.0f);
                float inter = iw * ih;
                iou = inter / (garea[g] + aa - inter + 1e-9f);
            }
            if (iou > best_iou) { best_iou = iou; best_g = g; }  // first-max wins
        }
        mrow[a] = (best_iou >= IOU_T) ? (signed char)best_g : (signed char)(-1);
    }

    // ---- pass 2: per-gt best anchor (wave owns 8 gts) ----
    const int wave = tid >> 6, lane = tid & 63;
    unsigned long long bk[8];
    #pragma unroll
    for (int j = 0; j < 8; ++j) bk[j] = 0ULL;

    for (int it = 0; it * 64 < MCH; ++it) {
        int a = a0 + it * 64 + lane;
        bool act = a < a1;
        int al = act ? a : (a0);            // safe address for inactive lanes
        float4 an = *(const float4*)(anchors + al * 4);
        float ax0 = an.x - an.z * 0.5f, ay0 = an.y - an.w * 0.5f;
        float ax1 = an.x + an.z * 0.5f, ay1 = an.y + an.w * 0.5f;
        float aa = (ax1 - ax0) * (ay1 - ay0);
        #pragma unroll
        for (int j = 0; j < 8; ++j) {
            int g = wave * 8 + j;
            if (!gvalid[g]) continue;       // wave-uniform branch
            float tlx = fmaxf(gx0[g], ax0), tly = fmaxf(gy0[g], ay0);
            float brx = fminf(gx1[g], ax1), bry = fminf(gy1[g], ay1);
            float iw = fmaxf(brx - tlx, 0.0f), ih = fmaxf(bry - tly, 0.0f);
            float inter = iw * ih;
            float iou = inter / (garea[g] + aa - inter + 1e-9f);
            unsigned long long key =
                ((unsigned long long)__float_as_uint(iou) << 32) |
                (unsigned)(0xFFFFFFFFu - (unsigned)a);
            if (act && key > bk[j]) bk[j] = key;
        }
    }
    #pragma unroll
    for (int j = 0; j < 8; ++j) {
        int g = wave * 8 + j;
        if (!gvalid[g]) continue;
        unsigned long long k = bk[j];
        for (int off = 32; off > 0; off >>= 1) {
            unsigned long long o = __shfl_down(k, off);
            if (o > k) k = o;
        }
        if (lane == 0 && k != 0ULL) atomicMax(&gbest[b * G + g], k);
    }
}

// ---------------------------------------------------------------------------
// K2: apply forced matches (sequential per batch, g ascending = last-wins).
// ---------------------------------------------------------------------------
__global__ void force_kernel(const unsigned long long* __restrict__ gbest,
                             const int* __restrict__ gt_labels,
                             signed char* __restrict__ matches)
{
    int b = threadIdx.x;
    if (b >= B) return;
    signed char* mrow = matches + (size_t)b * A;
    for (int g = 0; g < G; ++g) {
        if (gt_labels[b * G + g] <= 0) continue;
        unsigned a = 0xFFFFFFFFu - (unsigned)(gbest[b * G + g] & 0xFFFFFFFFu);
        signed char v = mrow[a];
        if (v < 0 || v >= 64) mrow[a] = (signed char)(64 + g);
    }
}

// ---------------------------------------------------------------------------
// K3: positive-side partial sums per (b, split) + negative-loss keys.
// grid (B, LSPLIT) x 256.  psplit fields: 0 pos_sum 1 box 2 lmk 3 gaze
//                                         4 pos_cnt 5 face_cnt
// ---------------------------------------------------------------------------
__global__ __launch_bounds__(256) void loss_split_kernel(
    const float* __restrict__ cls_logits, const float* __restrict__ box_preds,
    const float* __restrict__ lmk_preds, const float* __restrict__ gaze_preds,
    const float* __restrict__ anchors, const float* __restrict__ gt_boxes,
    const int* __restrict__ gt_labels, const float* __restrict__ gt_lmk,
    const float* __restrict__ gt_gaze, const signed char* __restrict__ matches,
    unsigned* __restrict__ negkey, float* __restrict__ psplit)
{
    const int b = blockIdx.x, s = blockIdx.y, tid = threadIdx.x;
    __shared__ float sgb[G * 4], slmk[G * NL * 2], sgz[G * 2];
    __shared__ int slab[G];
    __shared__ float red[256];

    for (int i = tid; i < G * 4; i += 256) sgb[i] = gt_boxes[b * G * 4 + i];
    for (int i = tid; i < G * NL * 2; i += 256) slmk[i] = gt_lmk[b * G * NL * 2 + i];
    for (int i = tid; i < G * 2; i += 256) sgz[i] = gt_gaze[b * G * 2 + i];
    if (tid < G) slab[tid] = gt_labels[b * G + tid];
    __syncthreads();

    const signed char* mrow = matches + (size_t)b * A;
    const float* lrow = cls_logits + (size_t)b * A * NC;
    unsigned* krow = negkey + (size_t)b * A;

    float pos_sum = 0, box_sum = 0, lmk_sum = 0, gaze_sum = 0;
    float pos_cnt = 0, face_cnt = 0;
    const int a0 = s * LCH, a1 = a0 + LCH;

    for (int a = a0 + tid; a < a1; a += 256) {
        int v = mrow[a];
        float x0 = lrow[a * 2], x1 = lrow[a * 2 + 1];
        float mx = fmaxf(x0, x1);
        float lse = mx + logf(expf(x0 - mx) + expf(x1 - mx));
        unsigned key = 0;
        if (v < 0) {
            float closs = lse - x0;   // label 0
            unsigned bits = __float_as_uint(closs);
            key = bits ^ ((bits & 0x80000000u) ? 0xFFFFFFFFu : 0x80000000u);
        } else {
            int m = v & 31;
            int lab = slab[m];
            float xc = (lab >= 1) ? x1 : x0;   // NC==2
            pos_sum += lse - xc;
            pos_cnt += 1.0f;
            float4 an = *(const float4*)(anchors + a * 4);
            float dcx = an.x, dcy = an.y, dw = an.z, dh = an.w;
            float bx0 = sgb[m * 4], by0 = sgb[m * 4 + 1];
            float bx1 = sgb[m * 4 + 2], by1 = sgb[m * 4 + 3];
            float gcx = (bx0 + bx1) * 0.5f, gcy = (by0 + by1) * 0.5f;
            float gw = bx1 - bx0, gh = by1 - by0;
            float off0 = ((gcx - dcx) / dw) / VAR_C;
            float off1 = ((gcy - dcy) / dh) / VAR_C;
            float off2 = logf(fmaxf(gw / dw, 1e-6f)) / VAR_S;
            float off3 = logf(fmaxf(gh / dh, 1e-6f)) / VAR_S;
            float4 bp = *(const float4*)(box_preds + ((size_t)b * A + a) * 4);
            box_sum += sl1(bp.x - off0) + sl1(bp.y - off1) +
                       sl1(bp.z - off2) + sl1(bp.w - off3);
            if (lab == 1) {  // FACE
                face_cnt += 1.0f;
                const float* lp = lmk_preds + ((size_t)b * A + a) * (NL * 2);
                #pragma unroll
                for (int i = 0; i < NL; ++i) {
                    float tx = ((slmk[m * NL * 2 + 2 * i] - dcx) / dw) / VAR_C;
                    float ty = ((slmk[m * NL * 2 + 2 * i + 1] - dcy) / dh) / VAR_C;
                    lmk_sum += sl1(lp[2 * i] - tx) + sl1(lp[2 * i + 1] - ty);
                }
                const float* gp = gaze_preds + ((size_t)b * A + a) * 2;
                gaze_sum += sl1(gp[0] - sgz[m * 2]) + sl1(gp[1] - sgz[m * 2 + 1]);
            }
        }
        krow[a] = key;
    }

    auto redf = [&](float v) -> float {
        red[tid] = v; __syncthreads();
        for (int st = 128; st > 0; st >>= 1) {
            if (tid < st) red[tid] += red[tid + st];
            __syncthreads();
        }
        float r = red[0]; __syncthreads();
        return r;
    };
    float f0 = redf(pos_sum), f1 = redf(box_sum), f2 = redf(lmk_sum);
    float f3 = redf(gaze_sum), f4 = redf(pos_cnt), f5 = redf(face_cnt);
    if (tid == 0) {
        float* pr = psplit + (b * LSPLIT + s) * PF;
        pr[0] = f0; pr[1] = f1; pr[2] = f2; pr[3] = f3; pr[4] = f4; pr[5] = f5;
    }
}

// ---------------------------------------------------------------------------
// K4: per-batch: reduce split partials, radix-select k-th largest negative
// loss from precomputed keys, sum top-k. grid B x 256.
// ---------------------------------------------------------------------------
__global__ __launch_bounds__(256) void select_kernel(
    const unsigned* __restrict__ negkey, const float* __restrict__ psplit,
    float* __restrict__ partials)
{
    const int b = blockIdx.x, tid = threadIdx.x;
    __shared__ float acc[PF];
    __shared__ unsigned hist[256];
    __shared__ unsigned s_pfx, s_k;
    __shared__ float red[256];

    if (tid < 6) {
        float v = 0;
        for (int s = 0; s < LSPLIT; ++s) v += psplit[(b * LSPLIT + s) * PF + tid];
        acc[tid] = v;
    }
    __syncthreads();

    unsigned pos_t = (unsigned)acc[4];
    unsigned face_t = (unsigned)acc[5];
    unsigned num_pos = pos_t > 1u ? pos_t : 1u;
    unsigned neg_cnt = (unsigned)A - pos_t;
    unsigned k = 3u * num_pos; if (neg_cnt < k) k = neg_cnt;

    const unsigned* krow = negkey + (size_t)b * A;
    unsigned pfx = 0, kk = k;
    for (int p = 0; p < 4; ++p) {
        hist[tid] = 0; __syncthreads();
        const int shift = 24 - 8 * p;
        for (int a = tid; a < A; a += 256) {
            unsigned key = krow[a];
            if (key != 0 && (p == 0 || (key >> (shift + 8)) == pfx))
                atomicAdd(&hist[(key >> shift) & 0xFFu], 1u);
        }
        __syncthreads();
        if (tid == 0) {
            unsigned cum = 0, sel = 0, kn = kk;
            for (int bin = 255; bin >= 0; --bin) {
                unsigned c = hist[bin];
                if (cum + c >= kk) { sel = (unsigned)bin; kn = kk - cum; break; }
                cum += c;
            }
            s_pfx = (pfx << 8) | sel; s_k = kn;
        }
        __syncthreads();
        pfx = s_pfx; kk = s_k;
    }
    const unsigned Tkey = pfx;
    const unsigned krem = kk;
    unsigned bitsT = (Tkey & 0x80000000u) ? (Tkey ^ 0x80000000u) : ~Tkey;
    const float Tval = __uint_as_float(bitsT);

    float nsum = 0;
    for (int a = tid; a < A; a += 256) {
        unsigned key = krow[a];
        if (key > Tkey) {
            unsigned bits = (key & 0x80000000u) ? (key ^ 0x80000000u) : ~key;
            nsum += __uint_as_float(bits);
        }
    }
    red[tid] = nsum; __syncthreads();
    for (int st = 128; st > 0; st >>= 1) {
        if (tid < st) red[tid] += red[tid + st];
        __syncthreads();
    }

    if (tid == 0) {
        float* pr = partials + b * PF;
        pr[0] = acc[0]; pr[1] = acc[1]; pr[2] = acc[2]; pr[3] = acc[3];
        pr[4] = red[0] + (float)krem * Tval;
        pr[5] = (float)num_pos;
        pr[6] = (float)(face_t > 1u ? face_t : 1u);
    }
}

// ---------------------------------------------------------------------------
// K5: combine per-batch partials -> 5 scalar outputs.
// ---------------------------------------------------------------------------
__global__ void finalize_kernel(const float* __restrict__ partials,
                                float* __restrict__ out)
{
    int t = threadIdx.x;  // 64 threads = 1 wave
    float ps = partials[t * PF + 0], bs = partials[t * PF + 1];
    float ls = partials[t * PF + 2], gs = partials[t * PF + 3];
    float ns = partials[t * PF + 4], npos = partials[t * PF + 5];
    float nf = partials[t * PF + 6];
    for (int o = 32; o > 0; o >>= 1) {
        ps += __shfl_down(ps, o); bs += __shfl_down(bs, o);
        ls += __shfl_down(ls, o); gs += __shfl_down(gs, o);
        ns += __shfl_down(ns, o); npos += __shfl_down(npos, o);
        nf += __shfl_down(nf, o);
    }
    if (t == 0) {
        float tc = (ps + ns) / npos;
        float tb = bs / npos;
        float tl = ls / nf;
        float tg = gs / nf;
        out[0] = tc + 1.0f * tb + 0.5f * tl + 1.0f * tg;
        out[1] = tc; out[2] = tb; out[3] = tl; out[4] = tg;
    }
}

extern "C" void kernel_launch(void* const* d_in, const int* in_sizes, int n_in,
                              void* d_out, int out_size, void* d_ws, size_t ws_size,
                              hipStream_t stream) {
    const float* cls_logits = (const float*)d_in[0];
    const float* box_preds  = (const float*)d_in[1];
    const float* lmk_preds  = (const float*)d_in[2];
    const float* gaze_preds = (const float*)d_in[3];
    const float* anchors    = (const float*)d_in[4];
    const float* gt_boxes   = (const float*)d_in[5];
    const int*   gt_labels  = (const int*)d_in[6];
    const float* gt_lmk     = (const float*)d_in[7];
    const float* gt_gaze    = (const float*)d_in[8];

    char* ws = (char*)d_ws;
    signed char* matches = (signed char*)ws;             ws += (size_t)B * A;             // 1.6 MB
    unsigned long long* gbest = (unsigned long long*)ws; ws += (size_t)B * G * 8;         // 16 KB
    unsigned* negkey = (unsigned*)ws;                    ws += (size_t)B * A * 4;         // 6.5 MB
    float* psplit = (float*)ws;                          ws += (size_t)B * LSPLIT * PF * 4;
    float* partials = (float*)ws;
    float* out = (float*)d_out;

    hipLaunchKernelGGL(init_kernel, dim3((B * G + 255) / 256), dim3(256), 0, stream, gbest);
    hipLaunchKernelGGL(match_kernel, dim3(B, MSPLIT), dim3(256), 0, stream,
                       anchors, gt_boxes, gt_labels, matches, gbest);
    hipLaunchKernelGGL(force_kernel, dim3(1), dim3(64), 0, stream,
                       gbest, gt_labels, matches);
    hipLaunchKernelGGL(loss_split_kernel, dim3(B, LSPLIT), dim3(256), 0, stream,
                       cls_logits, box_preds, lmk_preds, gaze_preds, anchors,
                       gt_boxes, gt_labels, gt_lmk, gt_gaze, matches, negkey, psplit);
    hipLaunchKernelGGL(select_kernel, dim3(B), dim3(256), 0, stream,
                       negkey, psplit, partials);
    hipLaunchKernelGGL(finalize_kernel, dim3(1), dim3(64), 0, stream,
                       partials, out);
}

// Round 4
// 146.369 us; speedup vs baseline: 4.2987x; 1.6531x over previous
//
#include <hip/hip_runtime.h>
#include <stdint.h>

#define B 64
#define G 32
#define A 25600
#define NC 2
#define NL 5
#define IOU_T 0.5f
#define VAR_C 0.1f
#define VAR_S 0.2f

#define MSPLIT 50
#define MCH (A / MSPLIT)    // 512 anchors per match block, 2 full 256-thr iters
#define LSPLIT 16
#define LCH (A / LSPLIT)    // 1600 anchors per loss block
#define PF 8                // fields per psplit record

#define NB 2048             // value-histogram bins
#define BSCALE 100.0f       // bin = int(closs * 100), clamped
#define CANDCAP 8192        // per-batch candidate buffer capacity

__device__ __forceinline__ float sl1(float x) {
    float ax = fabsf(x);
    return ax < 1.0f ? 0.5f * ax * ax : ax - 0.5f;
}

// ---------------------------------------------------------------------------
// K0: zero the per-gt best-anchor table.
// ---------------------------------------------------------------------------
__global__ void init_kernel(unsigned long long* __restrict__ gbest) {
    int i = blockIdx.x * blockDim.x + threadIdx.x;
    if (i < B * G) gbest[i] = 0ULL;
}

// ---------------------------------------------------------------------------
// K1: grid (B, MSPLIT) x 256.  FUSED single pass:
//  - per-anchor argmax over gts (registers) -> matches[b][a]
//  - per-gt best anchor: wave-level shfl max reduce + <=1 pre-checked LDS
//    atomic per (wave, gt); skipped when no lane intersects the gt.
// ---------------------------------------------------------------------------
__global__ __launch_bounds__(256) void match_kernel(
    const float* __restrict__ anchors, const float* __restrict__ gt_boxes,
    const int* __restrict__ gt_labels, signed char* __restrict__ matches,
    unsigned long long* __restrict__ gbest)
{
    const int b = blockIdx.x, s = blockIdx.y, tid = threadIdx.x;
    const int lane = tid & 63;
    __shared__ float gx0[G], gy0[G], gx1[G], gy1[G], garea[G];
    __shared__ int gvalid[G];
    __shared__ unsigned long long sbest[G];

    if (tid < G) {
        const float* gb = gt_boxes + (b * G + tid) * 4;
        float x0 = gb[0], y0 = gb[1], x1 = gb[2], y1 = gb[3];
        gx0[tid] = x0; gy0[tid] = y0; gx1[tid] = x1; gy1[tid] = y1;
        garea[tid] = (x1 - x0) * (y1 - y0);
        gvalid[tid] = gt_labels[b * G + tid] > 0;
        sbest[tid] = 0ULL;
    }
    __syncthreads();

    signed char* mrow = matches + (size_t)b * A;
    const int a0 = s * MCH;

    #pragma unroll
    for (int it = 0; it < MCH / 256; ++it) {
        const int a = a0 + it * 256 + tid;
        float4 an = *(const float4*)(anchors + a * 4);
        float ax0 = an.x - an.z * 0.5f, ay0 = an.y - an.w * 0.5f;
        float ax1 = an.x + an.z * 0.5f, ay1 = an.y + an.w * 0.5f;
        float aa = (ax1 - ax0) * (ay1 - ay0);   // mirror reference float path

        float best_iou = -2.0f; int best_g = 0;
        #pragma unroll
        for (int g = 0; g < G; ++g) {
            float iou = -1.0f;
            if (gvalid[g]) {                    // block-uniform branch
                float tlx = fmaxf(gx0[g], ax0), tly = fmaxf(gy0[g], ay0);
                float brx = fminf(gx1[g], ax1), bry = fminf(gy1[g], ay1);
                float iw = fmaxf(brx - tlx, 0.0f), ih = fmaxf(bry - tly, 0.0f);
                float inter = iw * ih;
                iou = 0.0f;                     // exact: 0/den == +0.0
                if (__any(inter > 0.0f)) {      // wave-uniform skip of div+reduce
                    iou = inter / (garea[g] + aa - inter + 1e-9f);
                    unsigned long long key =
                        ((unsigned long long)__float_as_uint(iou) << 32) |
                        (unsigned)(0xFFFFFFFFu - (unsigned)a);
                    #pragma unroll
                    for (int off = 32; off > 0; off >>= 1) {
                        unsigned long long o = __shfl_down(key, off);
                        if (o > key) key = o;
                    }
                    if (lane == 0 && key > sbest[g]) atomicMax(&sbest[g], key);
                }
            }
            if (iou > best_iou) { best_iou = iou; best_g = g; }  // first-max wins
        }
        mrow[a] = (best_iou >= IOU_T) ? (signed char)best_g : (signed char)(-1);
    }
    __syncthreads();
    if (tid < G && gvalid[tid] && sbest[tid] != 0ULL)
        atomicMax(&gbest[b * G + tid], sbest[tid]);
}

// ---------------------------------------------------------------------------
// K2: apply forced matches (sequential per batch, g ascending = last-wins).
// ---------------------------------------------------------------------------
__global__ void force_kernel(const unsigned long long* __restrict__ gbest,
                             const int* __restrict__ gt_labels,
                             signed char* __restrict__ matches)
{
    int b = threadIdx.x;
    if (b >= B) return;
    signed char* mrow = matches + (size_t)b * A;
    for (int g = 0; g < G; ++g) {
        if (gt_labels[b * G + g] <= 0) continue;
        unsigned long long kb = gbest[b * G + g];
        if (kb == 0ULL) continue;   // defensive: gt with no computed key
        unsigned a = 0xFFFFFFFFu - (unsigned)(kb & 0xFFFFFFFFu);
        signed char v = mrow[a];
        if (v < 0 || v >= 64) mrow[a] = (signed char)(64 + g);
    }
}

// ---------------------------------------------------------------------------
// K3: positive-side partial sums per (b, split) + negative-loss keys.
// grid (B, LSPLIT) x 256.
// ---------------------------------------------------------------------------
__global__ __launch_bounds__(256) void loss_split_kernel(
    const float* __restrict__ cls_logits, const float* __restrict__ box_preds,
    const float* __restrict__ lmk_preds, const float* __restrict__ gaze_preds,
    const float* __restrict__ anchors, const float* __restrict__ gt_boxes,
    const int* __restrict__ gt_labels, const float* __restrict__ gt_lmk,
    const float* __restrict__ gt_gaze, const signed char* __restrict__ matches,
    unsigned* __restrict__ negkey, float* __restrict__ psplit)
{
    const int b = blockIdx.x, s = blockIdx.y, tid = threadIdx.x;
    __shared__ float sgb[G * 4], slmk[G * NL * 2], sgz[G * 2];
    __shared__ int slab[G];
    __shared__ float red[256];

    for (int i = tid; i < G * 4; i += 256) sgb[i] = gt_boxes[b * G * 4 + i];
    for (int i = tid; i < G * NL * 2; i += 256) slmk[i] = gt_lmk[b * G * NL * 2 + i];
    for (int i = tid; i < G * 2; i += 256) sgz[i] = gt_gaze[b * G * 2 + i];
    if (tid < G) slab[tid] = gt_labels[b * G + tid];
    __syncthreads();

    const signed char* mrow = matches + (size_t)b * A;
    const float* lrow = cls_logits + (size_t)b * A * NC;
    unsigned* krow = negkey + (size_t)b * A;

    float pos_sum = 0, box_sum = 0, lmk_sum = 0, gaze_sum = 0;
    float pos_cnt = 0, face_cnt = 0;
    const int a0 = s * LCH, a1 = a0 + LCH;

    for (int a = a0 + tid; a < a1; a += 256) {
        int v = mrow[a];
        float x0 = lrow[a * 2], x1 = lrow[a * 2 + 1];
        float mx = fmaxf(x0, x1);
        float lse = mx + logf(expf(x0 - mx) + expf(x1 - mx));
        unsigned key = 0;
        if (v < 0) {
            float closs = lse - x0;   // label 0
            unsigned bits = __float_as_uint(closs);
            key = bits ^ ((bits & 0x80000000u) ? 0xFFFFFFFFu : 0x80000000u);
        } else {
            int m = v & 31;
            int lab = slab[m];
            float xc = (lab >= 1) ? x1 : x0;   // NC==2
            pos_sum += lse - xc;
            pos_cnt += 1.0f;
            float4 an = *(const float4*)(anchors + a * 4);
            float dcx = an.x, dcy = an.y, dw = an.z, dh = an.w;
            float bx0 = sgb[m * 4], by0 = sgb[m * 4 + 1];
            float bx1 = sgb[m * 4 + 2], by1 = sgb[m * 4 + 3];
            float gcx = (bx0 + bx1) * 0.5f, gcy = (by0 + by1) * 0.5f;
            float gw = bx1 - bx0, gh = by1 - by0;
            float off0 = ((gcx - dcx) / dw) / VAR_C;
            float off1 = ((gcy - dcy) / dh) / VAR_C;
            float off2 = logf(fmaxf(gw / dw, 1e-6f)) / VAR_S;
            float off3 = logf(fmaxf(gh / dh, 1e-6f)) / VAR_S;
            float4 bp = *(const float4*)(box_preds + ((size_t)b * A + a) * 4);
            box_sum += sl1(bp.x - off0) + sl1(bp.y - off1) +
                       sl1(bp.z - off2) + sl1(bp.w - off3);
            if (lab == 1) {  // FACE
                face_cnt += 1.0f;
                const float* lp = lmk_preds + ((size_t)b * A + a) * (NL * 2);
                #pragma unroll
                for (int i = 0; i < NL; ++i) {
                    float tx = ((slmk[m * NL * 2 + 2 * i] - dcx) / dw) / VAR_C;
                    float ty = ((slmk[m * NL * 2 + 2 * i + 1] - dcy) / dh) / VAR_C;
                    lmk_sum += sl1(lp[2 * i] - tx) + sl1(lp[2 * i + 1] - ty);
                }
                const float* gp = gaze_preds + ((size_t)b * A + a) * 2;
                gaze_sum += sl1(gp[0] - sgz[m * 2]) + sl1(gp[1] - sgz[m * 2 + 1]);
            }
        }
        krow[a] = key;
    }

    auto redf = [&](float v) -> float {
        red[tid] = v; __syncthreads();
        for (int st = 128; st > 0; st >>= 1) {
            if (tid < st) red[tid] += red[tid + st];
            __syncthreads();
        }
        float r = red[0]; __syncthreads();
        return r;
    };
    float f0 = redf(pos_sum), f1 = redf(box_sum), f2 = redf(lmk_sum);
    float f3 = redf(gaze_sum), f4 = redf(pos_cnt), f5 = redf(face_cnt);
    if (tid == 0) {
        float* pr = psplit + (b * LSPLIT + s) * PF;
        pr[0] = f0; pr[1] = f1; pr[2] = f2; pr[3] = f3; pr[4] = f4; pr[5] = f5;
    }
}

// ---------------------------------------------------------------------------
// K4: per-batch top-k negative sum via value-binned histogram + candidate
// compaction + exact radix over candidates + one deterministic sum scan.
// grid B x 256.
// ---------------------------------------------------------------------------
__global__ __launch_bounds__(256) void select_kernel(
    const unsigned* __restrict__ negkey, const float* __restrict__ psplit,
    unsigned* __restrict__ candbuf, float* __restrict__ partials)
{
    const int b = blockIdx.x, tid = threadIdx.x;
    __shared__ unsigned hist[NB];     // value hist; first 256 reused for radix
    __shared__ unsigned chunk[256];
    __shared__ float red[256];
    __shared__ float accs[8];
    __shared__ int s_t;
    __shared__ unsigned s_kk;
    __shared__ unsigned s_candN;
    __shared__ unsigned s_pfx, s_k2;

    const unsigned* krow = negkey + (size_t)b * A;
    const uint4* krow4 = (const uint4*)krow;
    unsigned* cand = candbuf + (size_t)b * CANDCAP;

    if (tid < 6) {
        float v = 0;
        for (int s2 = 0; s2 < LSPLIT; ++s2) v += psplit[(b * LSPLIT + s2) * PF + tid];
        accs[tid] = v;
    }
    for (int i = tid; i < NB; i += 256) hist[i] = 0;
    if (tid == 0) s_candN = 0;
    __syncthreads();

    // ---- scan 1: value histogram ----
    for (int it = 0; it < A / 1024; ++it) {
        uint4 kv = krow4[it * 256 + tid];
        #pragma unroll
        for (int j = 0; j < 4; ++j) {
            unsigned key = (&kv.x)[j];
            if (key != 0u) {
                float closs = __uint_as_float(key ^ 0x80000000u);
                int bin = (int)(closs * BSCALE);
                bin = bin < 0 ? 0 : (bin > NB - 1 ? NB - 1 : bin);
                atomicAdd(&hist[bin], 1u);
            }
        }
    }
    __syncthreads();

    unsigned pos_t = (unsigned)accs[4];
    unsigned face_t = (unsigned)accs[5];
    unsigned num_pos = pos_t > 1u ? pos_t : 1u;
    unsigned neg_cnt = (unsigned)A - pos_t;
    unsigned k = 3u * num_pos; if (neg_cnt < k) k = neg_cnt;

    // ---- suffix-scan: find threshold bin t, kk = rank within bin ----
    {
        unsigned csum = 0;
        #pragma unroll
        for (int j = 0; j < 8; ++j) csum += hist[tid * 8 + j];
        chunk[tid] = csum;
    }
    __syncthreads();
    if (tid == 0) {
        unsigned cum = 0; int tc = 0;
        for (int i = 255; i >= 0; --i) {
            if (cum + chunk[i] >= k) { tc = i; break; }
            cum += chunk[i];
        }
        int tt = tc * 8;
        for (int j = 7; j >= 0; --j) {
            unsigned h = hist[tc * 8 + j];
            if (cum + h >= k) { tt = tc * 8 + j; break; }
            cum += h;
        }
        s_t = tt; s_kk = k - cum;
    }
    __syncthreads();
    const int t = s_t;
    const unsigned kk_bin = s_kk;

    // ---- scan 2: compact bin==t candidates ----
    for (int it = 0; it < A / 1024; ++it) {
        uint4 kv = krow4[it * 256 + tid];
        #pragma unroll
        for (int j = 0; j < 4; ++j) {
            unsigned key = (&kv.x)[j];
            if (key != 0u) {
                float closs = __uint_as_float(key ^ 0x80000000u);
                int bin = (int)(closs * BSCALE);
                bin = bin < 0 ? 0 : (bin > NB - 1 ? NB - 1 : bin);
                if (bin == t) {
                    unsigned off = atomicAdd(&s_candN, 1u);
                    if (off < CANDCAP) cand[off] = key;
                }
            }
        }
    }
    __syncthreads();
    const unsigned candN = s_candN;
    const bool fast = candN <= CANDCAP;

    // ---- exact radix select of kk_bin-th largest within bin t ----
    unsigned pfx = 0, kk = kk_bin;
    for (int p = 0; p < 4; ++p) {
        if (tid < 256) hist[tid] = 0;
        __syncthreads();
        const int shift = 24 - 8 * p;
        if (fast) {
            for (unsigned i = tid; i < candN; i += 256) {
                unsigned key = cand[i];
                if (p == 0 || (key >> (shift + 8)) == pfx)
                    atomicAdd(&hist[(key >> shift) & 0xFFu], 1u);
            }
        } else {   // overflow fallback: scan full row with bin filter
            for (int a = tid; a < A; a += 256) {
                unsigned key = krow[a];
                if (key != 0u) {
                    float closs = __uint_as_float(key ^ 0x80000000u);
                    int bin = (int)(closs * BSCALE);
                    bin = bin < 0 ? 0 : (bin > NB - 1 ? NB - 1 : bin);
                    if (bin == t && (p == 0 || (key >> (shift + 8)) == pfx))
                        atomicAdd(&hist[(key >> shift) & 0xFFu], 1u);
                }
            }
        }
        __syncthreads();
        if (tid == 0) {
            unsigned cum2 = 0, sel = 0, kn = kk;
            for (int bin2 = 255; bin2 >= 0; --bin2) {
                unsigned c = hist[bin2];
                if (cum2 + c >= kk) { sel = (unsigned)bin2; kn = kk - cum2; break; }
                cum2 += c;
            }
            s_pfx = (pfx << 8) | sel; s_k2 = kn;
        }
        __syncthreads();
        pfx = s_pfx; kk = s_k2;
    }
    const unsigned Tkey = pfx;
    const unsigned krem = kk;
    const float Tval = __uint_as_float(Tkey ^ 0x80000000u);

    // ---- scan 3: deterministic fixed-stride sum ----
    float nsum = 0.0f;
    for (int it = 0; it < A / 1024; ++it) {
        uint4 kv = krow4[it * 256 + tid];
        #pragma unroll
        for (int j = 0; j < 4; ++j) {
            unsigned key = (&kv.x)[j];
            if (key != 0u) {
                float closs = __uint_as_float(key ^ 0x80000000u);
                int bin = (int)(closs * BSCALE);
                bin = bin < 0 ? 0 : (bin > NB - 1 ? NB - 1 : bin);
                if (bin > t || (bin == t && key > Tkey)) nsum += closs;
            }
        }
    }
    red[tid] = nsum; __syncthreads();
    for (int st = 128; st > 0; st >>= 1) {
        if (tid < st) red[tid] += red[tid + st];
        __syncthreads();
    }
    if (tid == 0) {
        float* pr = partials + b * PF;
        pr[0] = accs[0]; pr[1] = accs[1]; pr[2] = accs[2]; pr[3] = accs[3];
        pr[4] = red[0] + (float)krem * Tval;
        pr[5] = (float)num_pos;
        pr[6] = (float)(face_t > 1u ? face_t : 1u);
    }
}

// ---------------------------------------------------------------------------
// K5: combine per-batch partials -> 5 scalar outputs.
// ---------------------------------------------------------------------------
__global__ void finalize_kernel(const float* __restrict__ partials,
                                float* __restrict__ out)
{
    int t = threadIdx.x;  // 64 threads = 1 wave
    float ps = partials[t * PF + 0], bs = partials[t * PF + 1];
    float ls = partials[t * PF + 2], gs = partials[t * PF + 3];
    float ns = partials[t * PF + 4], npos = partials[t * PF + 5];
    float nf = partials[t * PF + 6];
    for (int o = 32; o > 0; o >>= 1) {
        ps += __shfl_down(ps, o); bs += __shfl_down(bs, o);
        ls += __shfl_down(ls, o); gs += __shfl_down(gs, o);
        ns += __shfl_down(ns, o); npos += __shfl_down(npos, o);
        nf += __shfl_down(nf, o);
    }
    if (t == 0) {
        float tc = (ps + ns) / npos;
        float tb = bs / npos;
        float tl = ls / nf;
        float tg = gs / nf;
        out[0] = tc + 1.0f * tb + 0.5f * tl + 1.0f * tg;
        out[1] = tc; out[2] = tb; out[3] = tl; out[4] = tg;
    }
}

extern "C" void kernel_launch(void* const* d_in, const int* in_sizes, int n_in,
                              void* d_out, int out_size, void* d_ws, size_t ws_size,
                              hipStream_t stream) {
    const float* cls_logits = (const float*)d_in[0];
    const float* box_preds  = (const float*)d_in[1];
    const float* lmk_preds  = (const float*)d_in[2];
    const float* gaze_preds = (const float*)d_in[3];
    const float* anchors    = (const float*)d_in[4];
    const float* gt_boxes   = (const float*)d_in[5];
    const int*   gt_labels  = (const int*)d_in[6];
    const float* gt_lmk     = (const float*)d_in[7];
    const float* gt_gaze    = (const float*)d_in[8];

    char* ws = (char*)d_ws;
    signed char* matches = (signed char*)ws;             ws += (size_t)B * A;              // 1.6 MB
    unsigned long long* gbest = (unsigned long long*)ws; ws += (size_t)B * G * 8;          // 16 KB
    unsigned* negkey = (unsigned*)ws;                    ws += (size_t)B * A * 4;          // 6.5 MB
    unsigned* candbuf = (unsigned*)ws;                   ws += (size_t)B * CANDCAP * 4;    // 2 MB
    float* psplit = (float*)ws;                          ws += (size_t)B * LSPLIT * PF * 4;
    float* partials = (float*)ws;
    float* out = (float*)d_out;

    hipLaunchKernelGGL(init_kernel, dim3((B * G + 255) / 256), dim3(256), 0, stream, gbest);
    hipLaunchKernelGGL(match_kernel, dim3(B, MSPLIT), dim3(256), 0, stream,
                       anchors, gt_boxes, gt_labels, matches, gbest);
    hipLaunchKernelGGL(force_kernel, dim3(1), dim3(64), 0, stream,
                       gbest, gt_labels, matches);
    hipLaunchKernelGGL(loss_split_kernel, dim3(B, LSPLIT), dim3(256), 0, stream,
                       cls_logits, box_preds, lmk_preds, gaze_preds, anchors,
                       gt_boxes, gt_labels, gt_lmk, gt_gaze, matches, negkey, psplit);
    hipLaunchKernelGGL(select_kernel, dim3(B), dim3(256), 0, stream,
                       negkey, psplit, candbuf, partials);
    hipLaunchKernelGGL(finalize_kernel, dim3(1), dim3(64), 0, stream,
                       partials, out);
}

// Round 5
// 94.504 us; speedup vs baseline: 6.6579x; 1.5488x over previous
//
#include <hip/hip_runtime.h>
#include <stdint.h>

#define B 64
#define G 32
#define A 25600
#define NC 2
#define NL 5
#define IOU_T 0.5f
#define VAR_C 0.1f
#define VAR_S 0.2f

#define MSPLIT 50
#define MCH (A / MSPLIT)    // 512 anchors per match block
#define LSPLIT 16
#define LCH (A / LSPLIT)    // 1600 anchors per loss block
#define PF 8                // fields per psplit record

#define NB 2048             // value-histogram bins
#define BSCALE 100.0f       // bin = int(closs * 100), clamped
#define CANDCAP 8192        // per-batch candidate buffer capacity
#define ST 512              // select_kernel threads

__device__ __forceinline__ float sl1(float x) {
    float ax = fabsf(x);
    return ax < 1.0f ? 0.5f * ax * ax : ax - 0.5f;
}

// ---------------------------------------------------------------------------
// K0: zero the per-gt best-anchor table.
// ---------------------------------------------------------------------------
__global__ void init_kernel(unsigned long long* __restrict__ gbest) {
    int i = blockIdx.x * blockDim.x + threadIdx.x;
    if (i < B * G) gbest[i] = 0ULL;
}

// ---------------------------------------------------------------------------
// K1: grid (B, MSPLIT) x 256.  FUSED single pass:
//  - per-anchor argmax over gts (registers) -> matches[b][a]
//  - per-gt best anchor: wave-level shfl max reduce + <=1 pre-checked LDS
//    atomic per (wave, gt); skipped when no lane intersects the gt.
// ---------------------------------------------------------------------------
__global__ __launch_bounds__(256) void match_kernel(
    const float* __restrict__ anchors, const float* __restrict__ gt_boxes,
    const int* __restrict__ gt_labels, signed char* __restrict__ matches,
    unsigned long long* __restrict__ gbest)
{
    const int b = blockIdx.x, s = blockIdx.y, tid = threadIdx.x;
    const int lane = tid & 63;
    __shared__ float gx0[G], gy0[G], gx1[G], gy1[G], garea[G];
    __shared__ int gvalid[G];
    __shared__ unsigned long long sbest[G];

    if (tid < G) {
        const float* gb = gt_boxes + (b * G + tid) * 4;
        float x0 = gb[0], y0 = gb[1], x1 = gb[2], y1 = gb[3];
        gx0[tid] = x0; gy0[tid] = y0; gx1[tid] = x1; gy1[tid] = y1;
        garea[tid] = (x1 - x0) * (y1 - y0);
        gvalid[tid] = gt_labels[b * G + tid] > 0;
        sbest[tid] = 0ULL;
    }
    __syncthreads();

    signed char* mrow = matches + (size_t)b * A;
    const int a0 = s * MCH;

    #pragma unroll
    for (int it = 0; it < MCH / 256; ++it) {
        const int a = a0 + it * 256 + tid;
        float4 an = *(const float4*)(anchors + a * 4);
        float ax0 = an.x - an.z * 0.5f, ay0 = an.y - an.w * 0.5f;
        float ax1 = an.x + an.z * 0.5f, ay1 = an.y + an.w * 0.5f;
        float aa = (ax1 - ax0) * (ay1 - ay0);   // mirror reference float path

        float best_iou = -2.0f; int best_g = 0;
        #pragma unroll
        for (int g = 0; g < G; ++g) {
            float iou = -1.0f;
            if (gvalid[g]) {                    // block-uniform branch
                float tlx = fmaxf(gx0[g], ax0), tly = fmaxf(gy0[g], ay0);
                float brx = fminf(gx1[g], ax1), bry = fminf(gy1[g], ay1);
                float iw = fmaxf(brx - tlx, 0.0f), ih = fmaxf(bry - tly, 0.0f);
                float inter = iw * ih;
                iou = 0.0f;                     // exact: 0/den == +0.0
                if (__any(inter > 0.0f)) {      // wave-uniform skip of div+reduce
                    iou = inter / (garea[g] + aa - inter + 1e-9f);
                    unsigned long long key =
                        ((unsigned long long)__float_as_uint(iou) << 32) |
                        (unsigned)(0xFFFFFFFFu - (unsigned)a);
                    #pragma unroll
                    for (int off = 32; off > 0; off >>= 1) {
                        unsigned long long o = __shfl_down(key, off);
                        if (o > key) key = o;
                    }
                    if (lane == 0 && key > sbest[g]) atomicMax(&sbest[g], key);
                }
            }
            if (iou > best_iou) { best_iou = iou; best_g = g; }  // first-max wins
        }
        mrow[a] = (best_iou >= IOU_T) ? (signed char)best_g : (signed char)(-1);
    }
    __syncthreads();
    if (tid < G && gvalid[tid] && sbest[tid] != 0ULL)
        atomicMax(&gbest[b * G + tid], sbest[tid]);
}

// ---------------------------------------------------------------------------
// K2: apply forced matches (sequential per batch, g ascending = last-wins).
// ---------------------------------------------------------------------------
__global__ void force_kernel(const unsigned long long* __restrict__ gbest,
                             const int* __restrict__ gt_labels,
                             signed char* __restrict__ matches)
{
    int b = threadIdx.x;
    if (b >= B) return;
    signed char* mrow = matches + (size_t)b * A;
    for (int g = 0; g < G; ++g) {
        if (gt_labels[b * G + g] <= 0) continue;
        unsigned long long kb = gbest[b * G + g];
        if (kb == 0ULL) continue;
        unsigned a = 0xFFFFFFFFu - (unsigned)(kb & 0xFFFFFFFFu);
        signed char v = mrow[a];
        if (v < 0 || v >= 64) mrow[a] = (signed char)(64 + g);
    }
}

// ---------------------------------------------------------------------------
// K3: positive-side partial sums per (b, split) + negative-loss keys.
// grid (B, LSPLIT) x 256.
// ---------------------------------------------------------------------------
__global__ __launch_bounds__(256) void loss_split_kernel(
    const float* __restrict__ cls_logits, const float* __restrict__ box_preds,
    const float* __restrict__ lmk_preds, const float* __restrict__ gaze_preds,
    const float* __restrict__ anchors, const float* __restrict__ gt_boxes,
    const int* __restrict__ gt_labels, const float* __restrict__ gt_lmk,
    const float* __restrict__ gt_gaze, const signed char* __restrict__ matches,
    unsigned* __restrict__ negkey, float* __restrict__ psplit)
{
    const int b = blockIdx.x, s = blockIdx.y, tid = threadIdx.x;
    __shared__ float sgb[G * 4], slmk[G * NL * 2], sgz[G * 2];
    __shared__ int slab[G];
    __shared__ float red[256];

    for (int i = tid; i < G * 4; i += 256) sgb[i] = gt_boxes[b * G * 4 + i];
    for (int i = tid; i < G * NL * 2; i += 256) slmk[i] = gt_lmk[b * G * NL * 2 + i];
    for (int i = tid; i < G * 2; i += 256) sgz[i] = gt_gaze[b * G * 2 + i];
    if (tid < G) slab[tid] = gt_labels[b * G + tid];
    __syncthreads();

    const signed char* mrow = matches + (size_t)b * A;
    const float* lrow = cls_logits + (size_t)b * A * NC;
    unsigned* krow = negkey + (size_t)b * A;

    float pos_sum = 0, box_sum = 0, lmk_sum = 0, gaze_sum = 0;
    float pos_cnt = 0, face_cnt = 0;
    const int a0 = s * LCH, a1 = a0 + LCH;

    for (int a = a0 + tid; a < a1; a += 256) {
        int v = mrow[a];
        float x0 = lrow[a * 2], x1 = lrow[a * 2 + 1];
        float mx = fmaxf(x0, x1);
        float lse = mx + logf(expf(x0 - mx) + expf(x1 - mx));
        unsigned key = 0;
        if (v < 0) {
            float closs = lse - x0;   // label 0
            unsigned bits = __float_as_uint(closs);
            key = bits ^ ((bits & 0x80000000u) ? 0xFFFFFFFFu : 0x80000000u);
        } else {
            int m = v & 31;
            int lab = slab[m];
            float xc = (lab >= 1) ? x1 : x0;   // NC==2
            pos_sum += lse - xc;
            pos_cnt += 1.0f;
            float4 an = *(const float4*)(anchors + a * 4);
            float dcx = an.x, dcy = an.y, dw = an.z, dh = an.w;
            float bx0 = sgb[m * 4], by0 = sgb[m * 4 + 1];
            float bx1 = sgb[m * 4 + 2], by1 = sgb[m * 4 + 3];
            float gcx = (bx0 + bx1) * 0.5f, gcy = (by0 + by1) * 0.5f;
            float gw = bx1 - bx0, gh = by1 - by0;
            float off0 = ((gcx - dcx) / dw) / VAR_C;
            float off1 = ((gcy - dcy) / dh) / VAR_C;
            float off2 = logf(fmaxf(gw / dw, 1e-6f)) / VAR_S;
            float off3 = logf(fmaxf(gh / dh, 1e-6f)) / VAR_S;
            float4 bp = *(const float4*)(box_preds + ((size_t)b * A + a) * 4);
            box_sum += sl1(bp.x - off0) + sl1(bp.y - off1) +
                       sl1(bp.z - off2) + sl1(bp.w - off3);
            if (lab == 1) {  // FACE
                face_cnt += 1.0f;
                const float* lp = lmk_preds + ((size_t)b * A + a) * (NL * 2);
                #pragma unroll
                for (int i = 0; i < NL; ++i) {
                    float tx = ((slmk[m * NL * 2 + 2 * i] - dcx) / dw) / VAR_C;
                    float ty = ((slmk[m * NL * 2 + 2 * i + 1] - dcy) / dh) / VAR_C;
                    lmk_sum += sl1(lp[2 * i] - tx) + sl1(lp[2 * i + 1] - ty);
                }
                const float* gp = gaze_preds + ((size_t)b * A + a) * 2;
                gaze_sum += sl1(gp[0] - sgz[m * 2]) + sl1(gp[1] - sgz[m * 2 + 1]);
            }
        }
        krow[a] = key;
    }

    auto redf = [&](float v) -> float {
        red[tid] = v; __syncthreads();
        for (int st = 128; st > 0; st >>= 1) {
            if (tid < st) red[tid] += red[tid + st];
            __syncthreads();
        }
        float r = red[0]; __syncthreads();
        return r;
    };
    float f0 = redf(pos_sum), f1 = redf(box_sum), f2 = redf(lmk_sum);
    float f3 = redf(gaze_sum), f4 = redf(pos_cnt), f5 = redf(face_cnt);
    if (tid == 0) {
        float* pr = psplit + (b * LSPLIT + s) * PF;
        pr[0] = f0; pr[1] = f1; pr[2] = f2; pr[3] = f3; pr[4] = f4; pr[5] = f5;
    }
}

// ---------------------------------------------------------------------------
// K4: per-batch top-k negative sum. grid B x 512. All bin walks are
// PARALLEL suffix scans (no serial tid==0 loops).
// ---------------------------------------------------------------------------
__global__ __launch_bounds__(ST) void select_kernel(
    const unsigned* __restrict__ negkey, const float* __restrict__ psplit,
    unsigned* __restrict__ candbuf, float* __restrict__ partials)
{
    const int b = blockIdx.x, tid = threadIdx.x;
    __shared__ unsigned hist[NB];
    __shared__ unsigned sc[ST];
    __shared__ float red[ST];
    __shared__ float accs[8];
    __shared__ int s_t;
    __shared__ unsigned s_kk;
    __shared__ unsigned s_candN;
    __shared__ unsigned s_pfx, s_k2;

    const unsigned* krow = negkey + (size_t)b * A;
    const uint4* krow4 = (const uint4*)krow;
    unsigned* cand = candbuf + (size_t)b * CANDCAP;

    if (tid < 6) {
        float v = 0;
        for (int s2 = 0; s2 < LSPLIT; ++s2) v += psplit[(b * LSPLIT + s2) * PF + tid];
        accs[tid] = v;
    }
    for (int i = tid; i < NB; i += ST) hist[i] = 0;
    if (tid == 0) s_candN = 0;
    __syncthreads();

    // ---- scan 1: value histogram ----
    for (int i = tid; i < A / 4; i += ST) {
        uint4 kv = krow4[i];
        #pragma unroll
        for (int j = 0; j < 4; ++j) {
            unsigned key = (&kv.x)[j];
            if (key != 0u) {
                float closs = __uint_as_float(key ^ 0x80000000u);
                int bin = (int)(closs * BSCALE);
                bin = bin < 0 ? 0 : (bin > NB - 1 ? NB - 1 : bin);
                atomicAdd(&hist[bin], 1u);
            }
        }
    }
    __syncthreads();

    unsigned pos_t = (unsigned)accs[4];
    unsigned face_t = (unsigned)accs[5];
    unsigned num_pos = pos_t > 1u ? pos_t : 1u;
    unsigned neg_cnt = (unsigned)A - pos_t;
    unsigned k = 3u * num_pos; if (neg_cnt < k) k = neg_cnt;

    // ---- parallel threshold find over NB bins (4 bins per thread) ----
    {
        unsigned c = hist[tid * 4] + hist[tid * 4 + 1] +
                     hist[tid * 4 + 2] + hist[tid * 4 + 3];
        sc[tid] = c; __syncthreads();
        #pragma unroll
        for (int off = 1; off < ST; off <<= 1) {
            unsigned add = (tid + off < ST) ? sc[tid + off] : 0u;
            __syncthreads();
            sc[tid] += add;
            __syncthreads();
        }
        unsigned excl = sc[tid] - c;          // count in strictly higher chunks
        if (excl < k && excl + c >= k) {      // unique owner
            unsigned cum = excl;
            #pragma unroll
            for (int j = 3; j >= 0; --j) {
                unsigned h = hist[tid * 4 + j];
                if (cum + h >= k) { s_t = tid * 4 + j; s_kk = k - cum; break; }
                cum += h;
            }
        }
        __syncthreads();
    }
    const int t = s_t;
    const unsigned kk_bin = s_kk;

    // ---- scan 2: sum bins>t, compact bin==t candidates ----
    float nsum_top = 0.0f;
    for (int i = tid; i < A / 4; i += ST) {
        uint4 kv = krow4[i];
        #pragma unroll
        for (int j = 0; j < 4; ++j) {
            unsigned key = (&kv.x)[j];
            if (key != 0u) {
                float closs = __uint_as_float(key ^ 0x80000000u);
                int bin = (int)(closs * BSCALE);
                bin = bin < 0 ? 0 : (bin > NB - 1 ? NB - 1 : bin);
                if (bin > t) {
                    nsum_top += closs;
                } else if (bin == t) {
                    unsigned off = atomicAdd(&s_candN, 1u);
                    if (off < CANDCAP) cand[off] = key;
                }
            }
        }
    }
    __syncthreads();
    const unsigned candN = s_candN;
    const bool fast = candN <= CANDCAP;

    // ---- exact radix select of kk_bin-th largest within bin t ----
    unsigned pfx = 0, kk = kk_bin;
    for (int p = 0; p < 4; ++p) {
        if (tid < 256) hist[tid] = 0;
        __syncthreads();
        const int shift = 24 - 8 * p;
        if (fast) {
            for (unsigned i = tid; i < candN; i += ST) {
                unsigned key = cand[i];
                if (p == 0 || (key >> (shift + 8)) == pfx)
                    atomicAdd(&hist[(key >> shift) & 0xFFu], 1u);
            }
        } else {   // overflow fallback: scan full row with bin filter
            for (int a = tid; a < A; a += ST) {
                unsigned key = krow[a];
                if (key != 0u) {
                    float closs = __uint_as_float(key ^ 0x80000000u);
                    int bin = (int)(closs * BSCALE);
                    bin = bin < 0 ? 0 : (bin > NB - 1 ? NB - 1 : bin);
                    if (bin == t && (p == 0 || (key >> (shift + 8)) == pfx))
                        atomicAdd(&hist[(key >> shift) & 0xFFu], 1u);
                }
            }
        }
        __syncthreads();
        // parallel suffix scan over 256 radix bins
        unsigned c = (tid < 256) ? hist[tid] : 0u;
        sc[tid] = c; __syncthreads();
        #pragma unroll
        for (int off = 1; off < ST; off <<= 1) {
            unsigned add = (tid + off < ST) ? sc[tid + off] : 0u;
            __syncthreads();
            sc[tid] += add;
            __syncthreads();
        }
        if (tid < 256) {
            unsigned excl = sc[tid] - c;
            if (excl < kk && excl + c >= kk) {   // unique owner
                s_pfx = (pfx << 8) | (unsigned)tid;
                s_k2 = kk - excl;
            }
        }
        __syncthreads();
        pfx = s_pfx; kk = s_k2;
        __syncthreads();
    }
    const unsigned Tkey = pfx;
    const unsigned krem = kk;
    const float Tval = __uint_as_float(Tkey ^ 0x80000000u);

    // ---- candidate sum (key > Tkey within bin t) ----
    float csum = 0.0f;
    if (fast) {
        for (unsigned i = tid; i < candN; i += ST) {
            unsigned key = cand[i];
            if (key > Tkey) csum += __uint_as_float(key ^ 0x80000000u);
        }
    } else {
        for (int a = tid; a < A; a += ST) {
            unsigned key = krow[a];
            if (key != 0u) {
                float closs = __uint_as_float(key ^ 0x80000000u);
                int bin = (int)(closs * BSCALE);
                bin = bin < 0 ? 0 : (bin > NB - 1 ? NB - 1 : bin);
                if (bin == t && key > Tkey) csum += closs;
            }
        }
    }
    red[tid] = nsum_top + csum; __syncthreads();
    for (int st = ST / 2; st > 0; st >>= 1) {
        if (tid < st) red[tid] += red[tid + st];
        __syncthreads();
    }
    if (tid == 0) {
        float* pr = partials + b * PF;
        pr[0] = accs[0]; pr[1] = accs[1]; pr[2] = accs[2]; pr[3] = accs[3];
        pr[4] = red[0] + (float)krem * Tval;
        pr[5] = (float)num_pos;
        pr[6] = (float)(face_t > 1u ? face_t : 1u);
    }
}

// ---------------------------------------------------------------------------
// K5: combine per-batch partials -> 5 scalar outputs.
// ---------------------------------------------------------------------------
__global__ void finalize_kernel(const float* __restrict__ partials,
                                float* __restrict__ out)
{
    int t = threadIdx.x;  // 64 threads = 1 wave
    float ps = partials[t * PF + 0], bs = partials[t * PF + 1];
    float ls = partials[t * PF + 2], gs = partials[t * PF + 3];
    float ns = partials[t * PF + 4], npos = partials[t * PF + 5];
    float nf = partials[t * PF + 6];
    for (int o = 32; o > 0; o >>= 1) {
        ps += __shfl_down(ps, o); bs += __shfl_down(bs, o);
        ls += __shfl_down(ls, o); gs += __shfl_down(gs, o);
        ns += __shfl_down(ns, o); npos += __shfl_down(npos, o);
        nf += __shfl_down(nf, o);
    }
    if (t == 0) {
        float tc = (ps + ns) / npos;
        float tb = bs / npos;
        float tl = ls / nf;
        float tg = gs / nf;
        out[0] = tc + 1.0f * tb + 0.5f * tl + 1.0f * tg;
        out[1] = tc; out[2] = tb; out[3] = tl; out[4] = tg;
    }
}

extern "C" void kernel_launch(void* const* d_in, const int* in_sizes, int n_in,
                              void* d_out, int out_size, void* d_ws, size_t ws_size,
                              hipStream_t stream) {
    const float* cls_logits = (const float*)d_in[0];
    const float* box_preds  = (const float*)d_in[1];
    const float* lmk_preds  = (const float*)d_in[2];
    const float* gaze_preds = (const float*)d_in[3];
    const float* anchors    = (const float*)d_in[4];
    const float* gt_boxes   = (const float*)d_in[5];
    const int*   gt_labels  = (const int*)d_in[6];
    const float* gt_lmk     = (const float*)d_in[7];
    const float* gt_gaze    = (const float*)d_in[8];

    char* ws = (char*)d_ws;
    signed char* matches = (signed char*)ws;             ws += (size_t)B * A;              // 1.6 MB
    unsigned long long* gbest = (unsigned long long*)ws; ws += (size_t)B * G * 8;          // 16 KB
    unsigned* negkey = (unsigned*)ws;                    ws += (size_t)B * A * 4;          // 6.5 MB
    unsigned* candbuf = (unsigned*)ws;                   ws += (size_t)B * CANDCAP * 4;    // 2 MB
    float* psplit = (float*)ws;                          ws += (size_t)B * LSPLIT * PF * 4;
    float* partials = (float*)ws;
    float* out = (float*)d_out;

    hipLaunchKernelGGL(init_kernel, dim3((B * G + 255) / 256), dim3(256), 0, stream, gbest);
    hipLaunchKernelGGL(match_kernel, dim3(B, MSPLIT), dim3(256), 0, stream,
                       anchors, gt_boxes, gt_labels, matches, gbest);
    hipLaunchKernelGGL(force_kernel, dim3(1), dim3(64), 0, stream,
                       gbest, gt_labels, matches);
    hipLaunchKernelGGL(loss_split_kernel, dim3(B, LSPLIT), dim3(256), 0, stream,
                       cls_logits, box_preds, lmk_preds, gaze_preds, anchors,
                       gt_boxes, gt_labels, gt_lmk, gt_gaze, matches, negkey, psplit);
    hipLaunchKernelGGL(select_kernel, dim3(B), dim3(ST), 0, stream,
                       negkey, psplit, candbuf, partials);
    hipLaunchKernelGGL(finalize_kernel, dim3(1), dim3(64), 0, stream,
                       partials, out);
}

// Round 6
// 66.904 us; speedup vs baseline: 9.4044x; 1.4125x over previous
//
#include <hip/hip_runtime.h>
#include <stdint.h>

#define B 64
#define G 32
#define A 25600
#define NC 2
#define NL 5
#define IOU_T 0.5f
#define VAR_C 0.1f
#define VAR_S 0.2f

#define MSPLIT 100
#define MCH (A / MSPLIT)    // 256 anchors per match block, 1 iter
#define LSPLIT 16
#define LCH (A / LSPLIT)    // 1600 anchors per loss block
#define PF 8                // fields per psplit record

#define NB 2048             // value-histogram bins
#define BSCALE 100.0f       // bin = int(closs * 100), clamped
#define CANDCAP 8192        // per-batch candidate buffer capacity
#define ST 512              // select_kernel threads

__device__ __forceinline__ float sl1(float x) {
    float ax = fabsf(x);
    return ax < 1.0f ? 0.5f * ax * ax : ax - 0.5f;
}

// ---------------------------------------------------------------------------
// K0: zero the per-gt best-anchor table.
// ---------------------------------------------------------------------------
__global__ void init_kernel(unsigned long long* __restrict__ gbest) {
    int i = blockIdx.x * blockDim.x + threadIdx.x;
    if (i < B * G) gbest[i] = 0ULL;
}

// ---------------------------------------------------------------------------
// K1: grid (B, MSPLIT) x 256.
//  - valid gts COMPACTED (ballot prefix) -> ~16 instead of 32 inner iters
//  - gt box packed float4 -> 1 ds_read_b128 per (wave,g), area recomputed
//    inline with the exact reference float formula
//  - per-anchor argmax (registers) -> matches[b][a]
//  - per-gt best anchor: wave shfl max reduce + <=1 LDS atomic per (wave,g),
//    skipped when no lane intersects; one global atomicMax per (block,gt).
// ---------------------------------------------------------------------------
__global__ __launch_bounds__(256) void match_kernel(
    const float* __restrict__ anchors, const float* __restrict__ gt_boxes,
    const int* __restrict__ gt_labels, signed char* __restrict__ matches,
    unsigned long long* __restrict__ gbest)
{
    const int b = blockIdx.x, s = blockIdx.y, tid = threadIdx.x;
    const int lane = tid & 63;
    __shared__ float4 sbox[G];          // compacted valid gt boxes
    __shared__ int sgorig[G];           // compacted -> original g
    __shared__ unsigned long long sbest[G];   // per compacted gt
    __shared__ int s_nv;

    if (tid < G) {
        sbest[tid] = 0ULL;
        int valid = gt_labels[b * G + tid] > 0;
        unsigned long long mask = __ballot(valid);   // lanes 0..31 active only
        int pfx = __popcll(mask & ((1ULL << tid) - 1ULL));
        if (valid) {
            sbox[pfx] = *(const float4*)(gt_boxes + (b * G + tid) * 4);
            sgorig[pfx] = tid;
        }
        if (tid == 0) s_nv = (int)__popcll(mask);
    }
    __syncthreads();
    const int nv = s_nv;

    signed char* mrow = matches + (size_t)b * A;
    const int a = s * MCH + tid;

    float4 an = *(const float4*)(anchors + a * 4);
    float ax0 = an.x - an.z * 0.5f, ay0 = an.y - an.w * 0.5f;
    float ax1 = an.x + an.z * 0.5f, ay1 = an.y + an.w * 0.5f;
    float aa = (ax1 - ax0) * (ay1 - ay0);   // mirror reference float path

    float best_iou = -2.0f; int best_ci = 0;
    for (int ci = 0; ci < nv; ++ci) {
        float4 bb = sbox[ci];                       // one ds_read_b128
        float area = (bb.z - bb.x) * (bb.w - bb.y); // reference formula
        float tlx = fmaxf(bb.x, ax0), tly = fmaxf(bb.y, ay0);
        float brx = fminf(bb.z, ax1), bry = fminf(bb.w, ay1);
        float iw = fmaxf(brx - tlx, 0.0f), ih = fmaxf(bry - tly, 0.0f);
        float inter = iw * ih;
        float iou = 0.0f;                           // exact: 0/den == +0.0
        if (__any(inter > 0.0f)) {                  // wave-uniform skip
            iou = inter / (area + aa - inter + 1e-9f);
            unsigned long long key =
                ((unsigned long long)__float_as_uint(iou) << 32) |
                (unsigned)(0xFFFFFFFFu - (unsigned)a);
            #pragma unroll
            for (int off = 32; off > 0; off >>= 1) {
                unsigned long long o = __shfl_down(key, off);
                if (o > key) key = o;
            }
            if (lane == 0 && key > sbest[ci]) atomicMax(&sbest[ci], key);
        }
        if (iou > best_iou) { best_iou = iou; best_ci = ci; }  // first-max wins
    }
    mrow[a] = (best_iou >= IOU_T) ? (signed char)sgorig[best_ci]
                                  : (signed char)(-1);
    __syncthreads();
    if (tid < nv && sbest[tid] != 0ULL)
        atomicMax(&gbest[b * G + sgorig[tid]], sbest[tid]);
}

// ---------------------------------------------------------------------------
// K2: positive-side partial sums per (b, split) + negative-loss keys.
// grid (B, LSPLIT) x 256.  Forced matches applied via per-block overlay
// built from gbest (atomicMax(int) -> max-g wins = reference last-wins;
// threshold matches take precedence since overlay only applies to mrow<0).
// ---------------------------------------------------------------------------
__global__ __launch_bounds__(256) void loss_split_kernel(
    const float* __restrict__ cls_logits, const float* __restrict__ box_preds,
    const float* __restrict__ lmk_preds, const float* __restrict__ gaze_preds,
    const float* __restrict__ anchors, const float* __restrict__ gt_boxes,
    const int* __restrict__ gt_labels, const float* __restrict__ gt_lmk,
    const float* __restrict__ gt_gaze, const signed char* __restrict__ matches,
    const unsigned long long* __restrict__ gbest,
    unsigned* __restrict__ negkey, float* __restrict__ psplit)
{
    const int b = blockIdx.x, s = blockIdx.y, tid = threadIdx.x;
    const int a0 = s * LCH, a1 = a0 + LCH;
    __shared__ float sgb[G * 4], slmk[G * NL * 2], sgz[G * 2];
    __shared__ int slab[G];
    __shared__ int fmap[LCH];           // forced overlay: -1 or g
    __shared__ float red[256];

    for (int i = tid; i < G * 4; i += 256) sgb[i] = gt_boxes[b * G * 4 + i];
    for (int i = tid; i < G * NL * 2; i += 256) slmk[i] = gt_lmk[b * G * NL * 2 + i];
    for (int i = tid; i < G * 2; i += 256) sgz[i] = gt_gaze[b * G + b * G + i - b * G];  // = gt_gaze[b*G*2 + i]
    if (tid < G) slab[tid] = gt_labels[b * G + tid];
    for (int i = tid; i < LCH; i += 256) fmap[i] = -1;
    __syncthreads();
    if (tid < G && slab[tid] > 0) {
        unsigned long long kb = gbest[b * G + tid];
        if (kb != 0ULL) {
            unsigned a = 0xFFFFFFFFu - (unsigned)(kb & 0xFFFFFFFFu);
            if ((int)a >= a0 && (int)a < a1)
                atomicMax(&fmap[a - a0], tid);   // max g = last-wins
        }
    }
    __syncthreads();

    const signed char* mrow = matches + (size_t)b * A;
    const float* lrow = cls_logits + (size_t)b * A * NC;
    unsigned* krow = negkey + (size_t)b * A;

    float pos_sum = 0, box_sum = 0, lmk_sum = 0, gaze_sum = 0;
    float pos_cnt = 0, face_cnt = 0;

    for (int a = a0 + tid; a < a1; a += 256) {
        int v = mrow[a];
        if (v < 0) v = fmap[a - a0];     // forced overlay (still -1 if none)
        float x0 = lrow[a * 2], x1 = lrow[a * 2 + 1];
        float mx = fmaxf(x0, x1);
        float lse = mx + logf(expf(x0 - mx) + expf(x1 - mx));
        unsigned key = 0;
        if (v < 0) {
            float closs = lse - x0;   // label 0
            unsigned bits = __float_as_uint(closs);
            key = bits ^ ((bits & 0x80000000u) ? 0xFFFFFFFFu : 0x80000000u);
        } else {
            int m = v;
            int lab = slab[m];
            float xc = (lab >= 1) ? x1 : x0;   // NC==2
            pos_sum += lse - xc;
            pos_cnt += 1.0f;
            float4 an = *(const float4*)(anchors + a * 4);
            float dcx = an.x, dcy = an.y, dw = an.z, dh = an.w;
            float bx0 = sgb[m * 4], by0 = sgb[m * 4 + 1];
            float bx1 = sgb[m * 4 + 2], by1 = sgb[m * 4 + 3];
            float gcx = (bx0 + bx1) * 0.5f, gcy = (by0 + by1) * 0.5f;
            float gw = bx1 - bx0, gh = by1 - by0;
            float off0 = ((gcx - dcx) / dw) / VAR_C;
            float off1 = ((gcy - dcy) / dh) / VAR_C;
            float off2 = logf(fmaxf(gw / dw, 1e-6f)) / VAR_S;
            float off3 = logf(fmaxf(gh / dh, 1e-6f)) / VAR_S;
            float4 bp = *(const float4*)(box_preds + ((size_t)b * A + a) * 4);
            box_sum += sl1(bp.x - off0) + sl1(bp.y - off1) +
                       sl1(bp.z - off2) + sl1(bp.w - off3);
            if (lab == 1) {  // FACE
                face_cnt += 1.0f;
                const float* lp = lmk_preds + ((size_t)b * A + a) * (NL * 2);
                #pragma unroll
                for (int i = 0; i < NL; ++i) {
                    float tx = ((slmk[m * NL * 2 + 2 * i] - dcx) / dw) / VAR_C;
                    float ty = ((slmk[m * NL * 2 + 2 * i + 1] - dcy) / dh) / VAR_C;
                    lmk_sum += sl1(lp[2 * i] - tx) + sl1(lp[2 * i + 1] - ty);
                }
                const float* gp = gaze_preds + ((size_t)b * A + a) * 2;
                gaze_sum += sl1(gp[0] - sgz[m * 2]) + sl1(gp[1] - sgz[m * 2 + 1]);
            }
        }
        krow[a] = key;
    }

    auto redf = [&](float v) -> float {
        red[tid] = v; __syncthreads();
        for (int st = 128; st > 0; st >>= 1) {
            if (tid < st) red[tid] += red[tid + st];
            __syncthreads();
        }
        float r = red[0]; __syncthreads();
        return r;
    };
    float f0 = redf(pos_sum), f1 = redf(box_sum), f2 = redf(lmk_sum);
    float f3 = redf(gaze_sum), f4 = redf(pos_cnt), f5 = redf(face_cnt);
    if (tid == 0) {
        float* pr = psplit + (b * LSPLIT + s) * PF;
        pr[0] = f0; pr[1] = f1; pr[2] = f2; pr[3] = f3; pr[4] = f4; pr[5] = f5;
    }
}

// ---------------------------------------------------------------------------
// K3: per-batch top-k negative sum. grid B x 512. All bin walks are
// PARALLEL suffix scans (no serial tid==0 loops).
// ---------------------------------------------------------------------------
__global__ __launch_bounds__(ST) void select_kernel(
    const unsigned* __restrict__ negkey, const float* __restrict__ psplit,
    unsigned* __restrict__ candbuf, float* __restrict__ partials)
{
    const int b = blockIdx.x, tid = threadIdx.x;
    __shared__ unsigned hist[NB];
    __shared__ unsigned sc[ST];
    __shared__ float red[ST];
    __shared__ float accs[8];
    __shared__ int s_t;
    __shared__ unsigned s_kk;
    __shared__ unsigned s_candN;
    __shared__ unsigned s_pfx, s_k2;

    const unsigned* krow = negkey + (size_t)b * A;
    const uint4* krow4 = (const uint4*)krow;
    unsigned* cand = candbuf + (size_t)b * CANDCAP;

    if (tid < 6) {
        float v = 0;
        for (int s2 = 0; s2 < LSPLIT; ++s2) v += psplit[(b * LSPLIT + s2) * PF + tid];
        accs[tid] = v;
    }
    for (int i = tid; i < NB; i += ST) hist[i] = 0;
    if (tid == 0) s_candN = 0;
    __syncthreads();

    // ---- scan 1: value histogram ----
    for (int i = tid; i < A / 4; i += ST) {
        uint4 kv = krow4[i];
        #pragma unroll
        for (int j = 0; j < 4; ++j) {
            unsigned key = (&kv.x)[j];
            if (key != 0u) {
                float closs = __uint_as_float(key ^ 0x80000000u);
                int bin = (int)(closs * BSCALE);
                bin = bin < 0 ? 0 : (bin > NB - 1 ? NB - 1 : bin);
                atomicAdd(&hist[bin], 1u);
            }
        }
    }
    __syncthreads();

    unsigned pos_t = (unsigned)accs[4];
    unsigned face_t = (unsigned)accs[5];
    unsigned num_pos = pos_t > 1u ? pos_t : 1u;
    unsigned neg_cnt = (unsigned)A - pos_t;
    unsigned k = 3u * num_pos; if (neg_cnt < k) k = neg_cnt;

    // ---- parallel threshold find over NB bins (4 bins per thread) ----
    {
        unsigned c = hist[tid * 4] + hist[tid * 4 + 1] +
                     hist[tid * 4 + 2] + hist[tid * 4 + 3];
        sc[tid] = c; __syncthreads();
        #pragma unroll
        for (int off = 1; off < ST; off <<= 1) {
            unsigned add = (tid + off < ST) ? sc[tid + off] : 0u;
            __syncthreads();
            sc[tid] += add;
            __syncthreads();
        }
        unsigned excl = sc[tid] - c;          // count in strictly higher chunks
        if (excl < k && excl + c >= k) {      // unique owner
            unsigned cum = excl;
            #pragma unroll
            for (int j = 3; j >= 0; --j) {
                unsigned h = hist[tid * 4 + j];
                if (cum + h >= k) { s_t = tid * 4 + j; s_kk = k - cum; break; }
                cum += h;
            }
        }
        __syncthreads();
    }
    const int t = s_t;
    const unsigned kk_bin = s_kk;

    // ---- scan 2: sum bins>t, compact bin==t candidates ----
    float nsum_top = 0.0f;
    for (int i = tid; i < A / 4; i += ST) {
        uint4 kv = krow4[i];
        #pragma unroll
        for (int j = 0; j < 4; ++j) {
            unsigned key = (&kv.x)[j];
            if (key != 0u) {
                float closs = __uint_as_float(key ^ 0x80000000u);
                int bin = (int)(closs * BSCALE);
                bin = bin < 0 ? 0 : (bin > NB - 1 ? NB - 1 : bin);
                if (bin > t) {
                    nsum_top += closs;
                } else if (bin == t) {
                    unsigned off = atomicAdd(&s_candN, 1u);
                    if (off < CANDCAP) cand[off] = key;
                }
            }
        }
    }
    __syncthreads();
    const unsigned candN = s_candN;
    const bool fast = candN <= CANDCAP;

    // ---- exact radix select of kk_bin-th largest within bin t ----
    unsigned pfx = 0, kk = kk_bin;
    for (int p = 0; p < 4; ++p) {
        if (tid < 256) hist[tid] = 0;
        __syncthreads();
        const int shift = 24 - 8 * p;
        if (fast) {
            for (unsigned i = tid; i < candN; i += ST) {
                unsigned key = cand[i];
                if (p == 0 || (key >> (shift + 8)) == pfx)
                    atomicAdd(&hist[(key >> shift) & 0xFFu], 1u);
            }
        } else {   // overflow fallback: scan full row with bin filter
            for (int a = tid; a < A; a += ST) {
                unsigned key = krow[a];
                if (key != 0u) {
                    float closs = __uint_as_float(key ^ 0x80000000u);
                    int bin = (int)(closs * BSCALE);
                    bin = bin < 0 ? 0 : (bin > NB - 1 ? NB - 1 : bin);
                    if (bin == t && (p == 0 || (key >> (shift + 8)) == pfx))
                        atomicAdd(&hist[(key >> shift) & 0xFFu], 1u);
                }
            }
        }
        __syncthreads();
        // parallel suffix scan over 256 radix bins
        unsigned c = (tid < 256) ? hist[tid] : 0u;
        sc[tid] = c; __syncthreads();
        #pragma unroll
        for (int off = 1; off < ST; off <<= 1) {
            unsigned add = (tid + off < ST) ? sc[tid + off] : 0u;
            __syncthreads();
            sc[tid] += add;
            __syncthreads();
        }
        if (tid < 256) {
            unsigned excl = sc[tid] - c;
            if (excl < kk && excl + c >= kk) {   // unique owner
                s_pfx = (pfx << 8) | (unsigned)tid;
                s_k2 = kk - excl;
            }
        }
        __syncthreads();
        pfx = s_pfx; kk = s_k2;
        __syncthreads();
    }
    const unsigned Tkey = pfx;
    const unsigned krem = kk;
    const float Tval = __uint_as_float(Tkey ^ 0x80000000u);

    // ---- candidate sum (key > Tkey within bin t) ----
    float csum = 0.0f;
    if (fast) {
        for (unsigned i = tid; i < candN; i += ST) {
            unsigned key = cand[i];
            if (key > Tkey) csum += __uint_as_float(key ^ 0x80000000u);
        }
    } else {
        for (int a = tid; a < A; a += ST) {
            unsigned key = krow[a];
            if (key != 0u) {
                float closs = __uint_as_float(key ^ 0x80000000u);
                int bin = (int)(closs * BSCALE);
                bin = bin < 0 ? 0 : (bin > NB - 1 ? NB - 1 : bin);
                if (bin == t && key > Tkey) csum += closs;
            }
        }
    }
    red[tid] = nsum_top + csum; __syncthreads();
    for (int st = ST / 2; st > 0; st >>= 1) {
        if (tid < st) red[tid] += red[tid + st];
        __syncthreads();
    }
    if (tid == 0) {
        float* pr = partials + b * PF;
        pr[0] = accs[0]; pr[1] = accs[1]; pr[2] = accs[2]; pr[3] = accs[3];
        pr[4] = red[0] + (float)krem * Tval;
        pr[5] = (float)num_pos;
        pr[6] = (float)(face_t > 1u ? face_t : 1u);
    }
}

// ---------------------------------------------------------------------------
// K4: combine per-batch partials -> 5 scalar outputs.
// ---------------------------------------------------------------------------
__global__ void finalize_kernel(const float* __restrict__ partials,
                                float* __restrict__ out)
{
    int t = threadIdx.x;  // 64 threads = 1 wave
    float ps = partials[t * PF + 0], bs = partials[t * PF + 1];
    float ls = partials[t * PF + 2], gs = partials[t * PF + 3];
    float ns = partials[t * PF + 4], npos = partials[t * PF + 5];
    float nf = partials[t * PF + 6];
    for (int o = 32; o > 0; o >>= 1) {
        ps += __shfl_down(ps, o); bs += __shfl_down(bs, o);
        ls += __shfl_down(ls, o); gs += __shfl_down(gs, o);
        ns += __shfl_down(ns, o); npos += __shfl_down(npos, o);
        nf += __shfl_down(nf, o);
    }
    if (t == 0) {
        float tc = (ps + ns) / npos;
        float tb = bs / npos;
        float tl = ls / nf;
        float tg = gs / nf;
        out[0] = tc + 1.0f * tb + 0.5f * tl + 1.0f * tg;
        out[1] = tc; out[2] = tb; out[3] = tl; out[4] = tg;
    }
}

extern "C" void kernel_launch(void* const* d_in, const int* in_sizes, int n_in,
                              void* d_out, int out_size, void* d_ws, size_t ws_size,
                              hipStream_t stream) {
    const float* cls_logits = (const float*)d_in[0];
    const float* box_preds  = (const float*)d_in[1];
    const float* lmk_preds  = (const float*)d_in[2];
    const float* gaze_preds = (const float*)d_in[3];
    const float* anchors    = (const float*)d_in[4];
    const float* gt_boxes   = (const float*)d_in[5];
    const int*   gt_labels  = (const int*)d_in[6];
    const float* gt_lmk     = (const float*)d_in[7];
    const float* gt_gaze    = (const float*)d_in[8];

    char* ws = (char*)d_ws;
    signed char* matches = (signed char*)ws;             ws += (size_t)B * A;              // 1.6 MB
    unsigned long long* gbest = (unsigned long long*)ws; ws += (size_t)B * G * 8;          // 16 KB
    unsigned* negkey = (unsigned*)ws;                    ws += (size_t)B * A * 4;          // 6.5 MB
    unsigned* candbuf = (unsigned*)ws;                   ws += (size_t)B * CANDCAP * 4;    // 2 MB
    float* psplit = (float*)ws;                          ws += (size_t)B * LSPLIT * PF * 4;
    float* partials = (float*)ws;
    float* out = (float*)d_out;

    hipLaunchKernelGGL(init_kernel, dim3((B * G + 255) / 256), dim3(256), 0, stream, gbest);
    hipLaunchKernelGGL(match_kernel, dim3(B, MSPLIT), dim3(256), 0, stream,
                       anchors, gt_boxes, gt_labels, matches, gbest);
    hipLaunchKernelGGL(loss_split_kernel, dim3(B, LSPLIT), dim3(256), 0, stream,
                       cls_logits, box_preds, lmk_preds, gaze_preds, anchors,
                       gt_boxes, gt_labels, gt_lmk, gt_gaze, matches, gbest,
                       negkey, psplit);
    hipLaunchKernelGGL(select_kernel, dim3(B), dim3(ST), 0, stream,
                       negkey, psplit, candbuf, partials);
    hipLaunchKernelGGL(finalize_kernel, dim3(1), dim3(64), 0, stream,
                       partials, out);
}